// Round 2
// baseline (23397.710 us; speedup 1.0000x reference)
//
#include <hip/hip_runtime.h>
#include <hip/hip_bf16.h>
#include <math.h>

// Problem constants
#define NT 32768
#define NFEATS 768
#define NHIDS 768
#define H 8
#define HD 96
#define DEG 8
#define NE (NT * DEG)
#define LRELU_ALPHA 0.2f

// ---------------------------------------------------------------------------
// Pack kernels (tiny, run once per launch)
// ---------------------------------------------------------------------------

// W2[f*768 + h*96 + d] = Wsrc[h][f][d]   (Wsrc is [H,768,96])
__global__ void packW(const float* __restrict__ Wsrc, float* __restrict__ Wdst) {
    int idx = blockIdx.x * 256 + threadIdx.x;
    if (idx >= 768 * 768) return;
    int f = idx / 768, c = idx % 768;
    int hh = c / HD, d = c % HD;
    Wdst[idx] = Wsrc[hh * 768 * HD + f * HD + d];
}

// GB[k][p*768 + c], p in 0..5:
//   p<3 : Wih^T chunk p  -> Wih[(p*768+c)*768 + k]
//   p>=3: Whh^T chunk p-3-> Whh[((p-3)*768+c)*768 + k]
__global__ void packGB(const float* __restrict__ Wih, const float* __restrict__ Whh,
                       float* __restrict__ GB) {
    int idx = blockIdx.x * 256 + threadIdx.x;
    if (idx >= 768 * 4608) return;
    int k = idx / 4608, j = idx % 4608;
    int p = j / 768, c = j % 768;
    float v;
    if (p < 3)  v = Wih[(size_t)(p * 768 + c) * 768 + k];
    else        v = Whh[(size_t)((p - 3) * 768 + c) * 768 + k];
    GB[idx] = v;
}

// ---------------------------------------------------------------------------
// f32 tiled GEMM with bias epilogue: C[M,N] = A[M,K] @ B[K,N] + bias[N]
// BM=BN=64, BK=16, 256 threads, 4x4 microtile.
// ---------------------------------------------------------------------------
#define BM 64
#define BN 64
#define BK 16

__global__ __launch_bounds__(256) void gemm_bias(
    const float* __restrict__ A, const float* __restrict__ B,
    const float* __restrict__ bias, float* __restrict__ C,
    int M, int N, int K) {
    __shared__ float As[BK][BM + 4];
    __shared__ float Bs[BK][BN];
    int bm = blockIdx.y, bn = blockIdx.x;
    int tid = threadIdx.x;
    int tx = tid % 16, ty = tid / 16;
    int arow_base = bm * BM;
    int bcol_base = bn * BN;
    float acc[4][4] = {};

    for (int k0 = 0; k0 < K; k0 += BK) {
        #pragma unroll
        for (int i = 0; i < 4; i++) {
            int r = (tid / 16) + i * 16;
            int kk = tid % 16;
            As[kk][r] = A[(size_t)(arow_base + r) * K + k0 + kk];
        }
        #pragma unroll
        for (int i = 0; i < 4; i++) {
            int r = (tid / 64) + i * 4;
            int c = tid % 64;
            Bs[r][c] = B[(size_t)(k0 + r) * N + bcol_base + c];
        }
        __syncthreads();
        #pragma unroll
        for (int kk = 0; kk < BK; kk++) {
            float a[4], b[4];
            #pragma unroll
            for (int i = 0; i < 4; i++) a[i] = As[kk][ty * 4 + i];
            #pragma unroll
            for (int j = 0; j < 4; j++) b[j] = Bs[kk][tx * 4 + j];
            #pragma unroll
            for (int i = 0; i < 4; i++)
                #pragma unroll
                for (int j = 0; j < 4; j++)
                    acc[i][j] += a[i] * b[j];
        }
        __syncthreads();
    }
    #pragma unroll
    for (int i = 0; i < 4; i++) {
        int r = arow_base + ty * 4 + i;
        #pragma unroll
        for (int j = 0; j < 4; j++) {
            int c = bcol_base + tx * 4 + j;
            C[(size_t)r * N + c] = acc[i][j] + bias[c];
        }
    }
}

// ---------------------------------------------------------------------------
// Edge score projections: sc[n*8+h] = sum_d X[n*768 + h*96 + d] * a[h*192 + half*96 + d]
// ---------------------------------------------------------------------------
__global__ __launch_bounds__(256) void escore(
    const float* __restrict__ X, const float* __restrict__ a,
    int half, float* __restrict__ sc) {
    __shared__ float av[768];
    for (int t = threadIdx.x; t < 768; t += 256) {
        int hh = t / HD, d = t % HD;
        av[t] = a[hh * 2 * HD + half * HD + d];
    }
    __syncthreads();
    int idx = blockIdx.x * 256 + threadIdx.x;   // (n,h)
    int row = idx >> 3, hh = idx & 7;
    const float* xp = X + (size_t)row * 768 + hh * HD;
    const float* ap = av + hh * HD;
    float s = 0.f;
    #pragma unroll
    for (int d = 0; d < HD; d++) s += xp[d] * ap[d];
    sc[idx] = s;
}

// ---------------------------------------------------------------------------
// Per-dst-node softmax over its 8 contiguous mailbox edges + weighted aggregate.
// out[dst] = beta*out[dst] + alpha * sum_j att[j] * Whs[src_j]
// ---------------------------------------------------------------------------
__global__ __launch_bounds__(256) void attend_agg(
    const float* __restrict__ Whs,   // [Ns, 768]
    const float* __restrict__ es,    // [Ns, 8]
    const float* __restrict__ ed,    // [Nd, 8]
    const float* __restrict__ ab,    // [8]
    const int* __restrict__ src,     // [E]
    const int* __restrict__ dst,     // [E]
    float* __restrict__ out,         // [Nd, 768]
    float alpha, float beta) {
    int i = blockIdx.x;              // segment (8 edges)
    int tid = threadIdx.x;
    __shared__ float att_s[64];
    __shared__ int src_s[8];
    __shared__ int dnode_s;
    if (tid < 8) src_s[tid] = src[i * 8 + tid];
    if (tid == 0) dnode_s = dst[i * 8];
    __syncthreads();
    int dnode = dnode_s;
    if (tid < 64) {
        int hh = tid >> 3;
        int j  = tid & 7;
        float e = es[(size_t)src_s[j] * 8 + hh] + ed[(size_t)dnode * 8 + hh] + ab[hh];
        e = e > 0.f ? e : LRELU_ALPHA * e;
        float m = e;
        #pragma unroll
        for (int o = 1; o < 8; o <<= 1) m = fmaxf(m, __shfl_xor(m, o, 64));
        float ex = expf(e - m);
        float s = ex;
        #pragma unroll
        for (int o = 1; o < 8; o <<= 1) s += __shfl_xor(s, o, 64);
        att_s[tid] = ex / s;
    }
    __syncthreads();
    #pragma unroll
    for (int u = 0; u < 3; u++) {
        int c = tid + u * 256;
        int hh = c / HD;
        float acc = 0.f;
        #pragma unroll
        for (int j = 0; j < 8; j++)
            acc += att_s[hh * 8 + j] * Whs[(size_t)src_s[j] * 768 + c];
        float r = alpha * acc;
        if (beta != 0.f) r += beta * out[(size_t)dnode * 768 + c];
        out[(size_t)dnode * 768 + c] = r;
    }
}

// ---------------------------------------------------------------------------
// Fused GRU: for each (n, c) computes
//   sr = x.Wih_r^T + hid.Whh_r^T ; sz = ... ; si = x.Wih_n^T ; sh = hid.Whh_n^T
//   r = sig(sr+b), z = sig(sz+b), cand = tanh(si+bih_n + r*(sh+bhh_n))
//   out = (1-z)*cand + z*hid
// GB is [768 k][6*768]: panels {Wih_r,Wih_z,Wih_n,Whh_r,Whh_z,Whh_n}^T
// ---------------------------------------------------------------------------
__global__ __launch_bounds__(256) void gru_fused(
    const float* __restrict__ X, const float* __restrict__ Hd,
    const float* __restrict__ GB,
    const float* __restrict__ bih, const float* __restrict__ bhh,
    float* __restrict__ out) {
    __shared__ float Xs[16][BM + 4];
    __shared__ float Hs[16][BM + 4];
    __shared__ float Bs[6][16][64];
    int bm = blockIdx.y, bn = blockIdx.x;   // bn in 0..11
    int tid = threadIdx.x;
    int tx = tid % 16, ty = tid / 16;
    int arow_base = bm * BM;
    int bcol_base = bn * 64;
    float ar[4][4] = {}, az[4][4] = {}, ai[4][4] = {}, ah[4][4] = {};

    for (int k0 = 0; k0 < 768; k0 += 16) {
        #pragma unroll
        for (int i = 0; i < 4; i++) {
            int r = (tid / 16) + i * 16;
            int kk = tid % 16;
            Xs[kk][r] = X[(size_t)(arow_base + r) * 768 + k0 + kk];
            Hs[kk][r] = Hd[(size_t)(arow_base + r) * 768 + k0 + kk];
        }
        #pragma unroll
        for (int p = 0; p < 6; p++) {
            #pragma unroll
            for (int i = 0; i < 4; i++) {
                int r = (tid / 64) + i * 4;
                int c = tid % 64;
                Bs[p][r][c] = GB[(size_t)(k0 + r) * 4608 + p * 768 + bcol_base + c];
            }
        }
        __syncthreads();
        #pragma unroll
        for (int kk = 0; kk < 16; kk++) {
            float xv[4], hv[4];
            #pragma unroll
            for (int i = 0; i < 4; i++) { xv[i] = Xs[kk][ty * 4 + i]; hv[i] = Hs[kk][ty * 4 + i]; }
            float b0[4], b1[4], b2[4], b3[4], b4[4], b5[4];
            #pragma unroll
            for (int j = 0; j < 4; j++) {
                b0[j] = Bs[0][kk][tx * 4 + j];
                b1[j] = Bs[1][kk][tx * 4 + j];
                b2[j] = Bs[2][kk][tx * 4 + j];
                b3[j] = Bs[3][kk][tx * 4 + j];
                b4[j] = Bs[4][kk][tx * 4 + j];
                b5[j] = Bs[5][kk][tx * 4 + j];
            }
            #pragma unroll
            for (int i = 0; i < 4; i++)
                #pragma unroll
                for (int j = 0; j < 4; j++) {
                    ar[i][j] += xv[i] * b0[j] + hv[i] * b3[j];
                    az[i][j] += xv[i] * b1[j] + hv[i] * b4[j];
                    ai[i][j] += xv[i] * b2[j];
                    ah[i][j] += hv[i] * b5[j];
                }
        }
        __syncthreads();
    }
    #pragma unroll
    for (int i = 0; i < 4; i++) {
        int row = arow_base + ty * 4 + i;
        #pragma unroll
        for (int j = 0; j < 4; j++) {
            int col = bcol_base + tx * 4 + j;
            float r = 1.f / (1.f + expf(-(ar[i][j] + bih[col] + bhh[col])));
            float z = 1.f / (1.f + expf(-(az[i][j] + bih[col + 768] + bhh[col + 768])));
            float cand = tanhf(ai[i][j] + bih[col + 1536] + r * (ah[i][j] + bhh[col + 1536]));
            float hv = Hd[(size_t)row * 768 + col];
            out[(size_t)row * 768 + col] = (1.f - z) * cand + z * hv;
        }
    }
}

// ---------------------------------------------------------------------------
// Launch
// Workspace layout (floats):
//   X   = ws            [NT*768]   x (intra-GAT output)
//   Hd  = ws +   SZ     [NT*768]   hid (0.5*h_c + 0.5*h_s)
//   packs at ws + 2*SZ:  W2g, W2x, GB, ES, ED, ESI, EDI  (~22 MB)
// Projection scratch P lives in d_out (dead until the final fused GRU).
// Total d_ws use: 2*SZ + 5.77M floats = ~224 MB.
// ---------------------------------------------------------------------------
extern "C" void kernel_launch(void* const* d_in, const int* in_sizes, int n_in,
                              void* d_out, int out_size, void* d_ws, size_t ws_size,
                              hipStream_t stream) {
    const float* h    = (const float*)d_in[0];
    const float* hbc  = (const float*)d_in[1];
    const float* hbs  = (const float*)d_in[2];
    const float* Wg   = (const float*)d_in[3];
    const float* bg   = (const float*)d_in[4];
    const float* ag   = (const float*)d_in[5];
    const float* agb  = (const float*)d_in[6];
    const float* Wx   = (const float*)d_in[7];
    const float* bx   = (const float*)d_in[8];
    const float* ax   = (const float*)d_in[9];
    const float* axb  = (const float*)d_in[10];
    const float* Wih  = (const float*)d_in[11];
    const float* Whh  = (const float*)d_in[12];
    const float* bih  = (const float*)d_in[13];
    const float* bhh  = (const float*)d_in[14];
    const int* i_src  = (const int*)d_in[15];
    const int* i_dst  = (const int*)d_in[16];
    const int* c_src  = (const int*)d_in[17];
    const int* c_dst  = (const int*)d_in[18];
    const int* s_src  = (const int*)d_in[19];
    const int* s_dst  = (const int*)d_in[20];
    float* out = (float*)d_out;
    float* ws  = (float*)d_ws;

    const size_t SZ = (size_t)NT * 768;
    float* X  = ws;             // x
    float* Hd = ws + SZ;        // hid
    float* P  = out;            // projection scratch (reuses d_out)
    float* sm = ws + 2 * SZ;
    float* W2g = sm;            sm += 768 * 768;
    float* W2x = sm;            sm += 768 * 768;
    float* GB  = sm;            sm += 768 * 4608;
    float* ES  = sm;            sm += NT * 8;
    float* ED  = sm;            sm += NT * 8;
    float* ESI = sm;            sm += NT * 8;
    float* EDI = sm;            sm += NT * 8;

    dim3 blk(256);
    packW<<<(768 * 768 + 255) / 256, blk, 0, stream>>>(Wg, W2g);
    packW<<<(768 * 768 + 255) / 256, blk, 0, stream>>>(Wx, W2x);
    packGB<<<(768 * 4608 + 255) / 256, blk, 0, stream>>>(Wih, Whh, GB);

    dim3 g768(768 / BN, NT / BM);     // (12, 512)

    // 1) Wh = h @ W2g + bg -> P
    gemm_bias<<<g768, blk, 0, stream>>>(h, W2g, bg, P, NT, 768, 768);
    // 2) intra scores + attend -> x
    escore<<<NE / 256, blk, 0, stream>>>(P, ag, 0, ESI);
    escore<<<NE / 256, blk, 0, stream>>>(P, ag, 1, EDI);
    attend_agg<<<NT, blk, 0, stream>>>(P, ESI, EDI, agb, i_src, i_dst, X, 1.f, 0.f);
    // 3) Wx_d = x @ W2x + bx -> P ; dst scores
    gemm_bias<<<g768, blk, 0, stream>>>(X, W2x, bx, P, NT, 768, 768);
    escore<<<NE / 256, blk, 0, stream>>>(P, ax, 1, ED);
    // 4) counter branch: Wc_s -> P, attend -> Hd (0.5, overwrite)
    gemm_bias<<<g768, blk, 0, stream>>>(hbc, W2x, bx, P, NT, 768, 768);
    escore<<<NE / 256, blk, 0, stream>>>(P, ax, 0, ES);
    attend_agg<<<NT, blk, 0, stream>>>(P, ES, ED, axb, c_src, c_dst, Hd, 0.5f, 0.f);
    // 5) support branch: Ws_s -> P, attend -> Hd (0.5, accumulate)
    gemm_bias<<<g768, blk, 0, stream>>>(hbs, W2x, bx, P, NT, 768, 768);
    escore<<<NE / 256, blk, 0, stream>>>(P, ax, 0, ES);
    attend_agg<<<NT, blk, 0, stream>>>(P, ES, ED, axb, s_src, s_dst, Hd, 0.5f, 1.f);
    // 6) fused GRU -> out
    gru_fused<<<g768, blk, 0, stream>>>(X, Hd, GB, bih, bhh, out);
}

// Round 3
// 6121.784 us; speedup vs baseline: 3.8220x; 3.8220x over previous
//
#include <hip/hip_runtime.h>
#include <hip/hip_bf16.h>
#include <math.h>

// Problem constants
#define NT 32768
#define NFEATS 768
#define NHIDS 768
#define H 8
#define HD 96
#define DEG 8
#define NE (NT * DEG)
#define LRELU_ALPHA 0.2f
#define CH 2048              // GRU row-chunk

// ---------------------------------------------------------------------------
// Pack kernels (tiny, run once per launch)
// ---------------------------------------------------------------------------

// W2[f*768 + h*96 + d] = Wsrc[h][f][d]   (Wsrc is [H,768,96])
__global__ void packW(const float* __restrict__ Wsrc, float* __restrict__ Wdst) {
    int idx = blockIdx.x * 256 + threadIdx.x;
    if (idx >= 768 * 768) return;
    int f = idx / 768, c = idx % 768;
    int hh = c / HD, d = c % HD;
    Wdst[idx] = Wsrc[hh * 768 * HD + f * HD + d];
}

// T[f*N + c] = W[c*768 + f]   (W is [N,768] row-major; T = W^T as [768][N])
__global__ void packT(const float* __restrict__ W, float* __restrict__ T, int N) {
    int idx = blockIdx.x * 256 + threadIdx.x;
    if (idx >= 768 * N) return;
    int f = idx / N, c = idx % N;
    T[idx] = W[(size_t)c * 768 + f];
}

// ---------------------------------------------------------------------------
// f32 tiled GEMM with bias epilogue: C[M,N] = A[M,K] @ B[K,N] + bias[N]
// BM=BN=64, BK=16, 256 threads, 4x4 microtile.  (proven round-2 kernel)
// ---------------------------------------------------------------------------
#define BM 64
#define BN 64
#define BK 16

__global__ __launch_bounds__(256) void gemm_bias(
    const float* __restrict__ A, const float* __restrict__ B,
    const float* __restrict__ bias, float* __restrict__ C,
    int M, int N, int K) {
    __shared__ float As[BK][BM + 4];
    __shared__ float Bs[BK][BN];
    int bm = blockIdx.y, bn = blockIdx.x;
    int tid = threadIdx.x;
    int tx = tid % 16, ty = tid / 16;
    int arow_base = bm * BM;
    int bcol_base = bn * BN;
    float acc[4][4] = {};

    for (int k0 = 0; k0 < K; k0 += BK) {
        #pragma unroll
        for (int i = 0; i < 4; i++) {
            int r = (tid / 16) + i * 16;
            int kk = tid % 16;
            As[kk][r] = A[(size_t)(arow_base + r) * K + k0 + kk];
        }
        #pragma unroll
        for (int i = 0; i < 4; i++) {
            int r = (tid / 64) + i * 4;
            int c = tid % 64;
            Bs[r][c] = B[(size_t)(k0 + r) * N + bcol_base + c];
        }
        __syncthreads();
        #pragma unroll
        for (int kk = 0; kk < BK; kk++) {
            float a[4], b[4];
            #pragma unroll
            for (int i = 0; i < 4; i++) a[i] = As[kk][ty * 4 + i];
            #pragma unroll
            for (int j = 0; j < 4; j++) b[j] = Bs[kk][tx * 4 + j];
            #pragma unroll
            for (int i = 0; i < 4; i++)
                #pragma unroll
                for (int j = 0; j < 4; j++)
                    acc[i][j] += a[i] * b[j];
        }
        __syncthreads();
    }
    #pragma unroll
    for (int i = 0; i < 4; i++) {
        int r = arow_base + ty * 4 + i;
        #pragma unroll
        for (int j = 0; j < 4; j++) {
            int c = bcol_base + tx * 4 + j;
            C[(size_t)r * N + c] = acc[i][j] + bias[c];
        }
    }
}

// ---------------------------------------------------------------------------
// Edge score projections: sc[n*8+h] = sum_d X[n*768 + h*96 + d] * a[h*192 + half*96 + d]
// ---------------------------------------------------------------------------
__global__ __launch_bounds__(256) void escore(
    const float* __restrict__ X, const float* __restrict__ a,
    int half, float* __restrict__ sc) {
    __shared__ float av[768];
    for (int t = threadIdx.x; t < 768; t += 256) {
        int hh = t / HD, d = t % HD;
        av[t] = a[hh * 2 * HD + half * HD + d];
    }
    __syncthreads();
    int idx = blockIdx.x * 256 + threadIdx.x;   // (n,h)
    int row = idx >> 3, hh = idx & 7;
    const float* xp = X + (size_t)row * 768 + hh * HD;
    const float* ap = av + hh * HD;
    float s = 0.f;
    #pragma unroll
    for (int d = 0; d < HD; d++) s += xp[d] * ap[d];
    sc[idx] = s;
}

// ---------------------------------------------------------------------------
// Per-dst-node softmax over its 8 contiguous mailbox edges + weighted aggregate.
// out[dst] = beta*out[dst] + alpha * sum_j att[j] * Whs[src_j]
// ---------------------------------------------------------------------------
__global__ __launch_bounds__(256) void attend_agg(
    const float* __restrict__ Whs,   // [Ns, 768]
    const float* __restrict__ es,    // [Ns, 8]
    const float* __restrict__ ed,    // [Nd, 8]
    const float* __restrict__ ab,    // [8]
    const int* __restrict__ src,     // [E]
    const int* __restrict__ dst,     // [E]
    float* __restrict__ out,         // [Nd, 768]
    float alpha, float beta) {
    int i = blockIdx.x;              // segment (8 edges)
    int tid = threadIdx.x;
    __shared__ float att_s[64];
    __shared__ int src_s[8];
    __shared__ int dnode_s;
    if (tid < 8) src_s[tid] = src[i * 8 + tid];
    if (tid == 0) dnode_s = dst[i * 8];
    __syncthreads();
    int dnode = dnode_s;
    if (tid < 64) {
        int hh = tid >> 3;
        int j  = tid & 7;
        float e = es[(size_t)src_s[j] * 8 + hh] + ed[(size_t)dnode * 8 + hh] + ab[hh];
        e = e > 0.f ? e : LRELU_ALPHA * e;
        float m = e;
        #pragma unroll
        for (int o = 1; o < 8; o <<= 1) m = fmaxf(m, __shfl_xor(m, o, 64));
        float ex = expf(e - m);
        float s = ex;
        #pragma unroll
        for (int o = 1; o < 8; o <<= 1) s += __shfl_xor(s, o, 64);
        att_s[tid] = ex / s;
    }
    __syncthreads();
    #pragma unroll
    for (int u = 0; u < 3; u++) {
        int c = tid + u * 256;
        int hh = c / HD;
        float acc = 0.f;
        #pragma unroll
        for (int j = 0; j < 8; j++)
            acc += att_s[hh * 8 + j] * Whs[(size_t)src_s[j] * 768 + c];
        float r = alpha * acc;
        if (beta != 0.f) r += beta * out[(size_t)dnode * 768 + c];
        out[(size_t)dnode * 768 + c] = r;
    }
}

// ---------------------------------------------------------------------------
// GRU elementwise tail for one row-chunk.
// gi/gh: [rows, 2304] chunk-local; hid/out: pointers offset to chunk start.
// ---------------------------------------------------------------------------
__global__ __launch_bounds__(256) void gru_elem(
    const float* __restrict__ gi, const float* __restrict__ gh,
    const float* __restrict__ hid, float* __restrict__ out) {
    int idx = blockIdx.x * 256 + threadIdx.x;   // over rows*768
    int nrow = idx / 768, c = idx % 768;
    const float* gip = gi + (size_t)nrow * 2304;
    const float* ghp = gh + (size_t)nrow * 2304;
    float ir  = gip[c],        hr = ghp[c];
    float iz  = gip[768 + c],  hz = ghp[768 + c];
    float in_ = gip[1536 + c], hn = ghp[1536 + c];
    float r = 1.f / (1.f + expf(-(ir + hr)));
    float z = 1.f / (1.f + expf(-(iz + hz)));
    float cand = tanhf(in_ + r * hn);
    float hv = hid[idx];
    out[idx] = (1.f - z) * cand + z * hv;
}

// ---------------------------------------------------------------------------
// Launch
// Workspace layout (floats):
//   X   = ws          [NT*768]       x (intra-GAT output)
//   Hd  = ws +  SZ    [NT*768]       hid
//   GI  = ws + 2*SZ   [CH*2304]      gi chunk
//   GH  = GI + CH*2304 [CH*2304]     gh chunk
//   packs after: W2g, W2x, WihT, WhhT, ES, ED, ESI, EDI
// Projection scratch P lives in d_out (dead until final GRU writes it).
// Total d_ws: 2*SZ + 2*CH*2304 + ~7.3M floats ≈ 262 MB.
// ---------------------------------------------------------------------------
extern "C" void kernel_launch(void* const* d_in, const int* in_sizes, int n_in,
                              void* d_out, int out_size, void* d_ws, size_t ws_size,
                              hipStream_t stream) {
    const float* h    = (const float*)d_in[0];
    const float* hbc  = (const float*)d_in[1];
    const float* hbs  = (const float*)d_in[2];
    const float* Wg   = (const float*)d_in[3];
    const float* bg   = (const float*)d_in[4];
    const float* ag   = (const float*)d_in[5];
    const float* agb  = (const float*)d_in[6];
    const float* Wx   = (const float*)d_in[7];
    const float* bx   = (const float*)d_in[8];
    const float* ax   = (const float*)d_in[9];
    const float* axb  = (const float*)d_in[10];
    const float* Wih  = (const float*)d_in[11];
    const float* Whh  = (const float*)d_in[12];
    const float* bih  = (const float*)d_in[13];
    const float* bhh  = (const float*)d_in[14];
    const int* i_src  = (const int*)d_in[15];
    const int* i_dst  = (const int*)d_in[16];
    const int* c_src  = (const int*)d_in[17];
    const int* c_dst  = (const int*)d_in[18];
    const int* s_src  = (const int*)d_in[19];
    const int* s_dst  = (const int*)d_in[20];
    float* out = (float*)d_out;
    float* ws  = (float*)d_ws;

    const size_t SZ = (size_t)NT * 768;
    float* X   = ws;
    float* Hd  = ws + SZ;
    float* GI  = ws + 2 * SZ;
    float* GH  = GI + (size_t)CH * 2304;
    float* P   = out;                       // projection scratch (reuses d_out)
    float* sm  = GH + (size_t)CH * 2304;
    float* W2g  = sm;            sm += 768 * 768;
    float* W2x  = sm;            sm += 768 * 768;
    float* WihT = sm;            sm += 768 * 2304;
    float* WhhT = sm;            sm += 768 * 2304;
    float* ES   = sm;            sm += NT * 8;
    float* ED   = sm;            sm += NT * 8;
    float* ESI  = sm;            sm += NT * 8;
    float* EDI  = sm;            sm += NT * 8;

    dim3 blk(256);
    packW<<<(768 * 768 + 255) / 256, blk, 0, stream>>>(Wg, W2g);
    packW<<<(768 * 768 + 255) / 256, blk, 0, stream>>>(Wx, W2x);
    packT<<<(768 * 2304 + 255) / 256, blk, 0, stream>>>(Wih, WihT, 2304);
    packT<<<(768 * 2304 + 255) / 256, blk, 0, stream>>>(Whh, WhhT, 2304);

    dim3 g768(768 / BN, NT / BM);     // (12, 512)

    // 1) Wh = h @ W2g + bg -> P
    gemm_bias<<<g768, blk, 0, stream>>>(h, W2g, bg, P, NT, 768, 768);
    // 2) intra scores + attend -> x
    escore<<<NE / 256, blk, 0, stream>>>(P, ag, 0, ESI);
    escore<<<NE / 256, blk, 0, stream>>>(P, ag, 1, EDI);
    attend_agg<<<NT, blk, 0, stream>>>(P, ESI, EDI, agb, i_src, i_dst, X, 1.f, 0.f);
    // 3) Wx_d = x @ W2x + bx -> P ; dst scores
    gemm_bias<<<g768, blk, 0, stream>>>(X, W2x, bx, P, NT, 768, 768);
    escore<<<NE / 256, blk, 0, stream>>>(P, ax, 1, ED);
    // 4) counter branch: Wc_s -> P, attend -> Hd (0.5, overwrite)
    gemm_bias<<<g768, blk, 0, stream>>>(hbc, W2x, bx, P, NT, 768, 768);
    escore<<<NE / 256, blk, 0, stream>>>(P, ax, 0, ES);
    attend_agg<<<NT, blk, 0, stream>>>(P, ES, ED, axb, c_src, c_dst, Hd, 0.5f, 0.f);
    // 5) support branch: Ws_s -> P, attend -> Hd (0.5, accumulate)
    gemm_bias<<<g768, blk, 0, stream>>>(hbs, W2x, bx, P, NT, 768, 768);
    escore<<<NE / 256, blk, 0, stream>>>(P, ax, 0, ES);
    attend_agg<<<NT, blk, 0, stream>>>(P, ES, ED, axb, s_src, s_dst, Hd, 0.5f, 1.f);

    // 6) GRU, row-chunked: gi/gh chunk GEMMs + fused elementwise
    dim3 gch(2304 / BN, CH / BM);     // (36, 32)
    for (int c0 = 0; c0 < NT; c0 += CH) {
        const float* Xc  = X  + (size_t)c0 * 768;
        const float* Hc  = Hd + (size_t)c0 * 768;
        gemm_bias<<<gch, blk, 0, stream>>>(Xc, WihT, bih, GI, CH, 2304, 768);
        gemm_bias<<<gch, blk, 0, stream>>>(Hc, WhhT, bhh, GH, CH, 2304, 768);
        gru_elem<<<(CH * 768) / 256, blk, 0, stream>>>(GI, GH, Hc, out + (size_t)c0 * 768);
    }
}

// Round 4
// 1836.660 us; speedup vs baseline: 12.7393x; 3.3331x over previous
//
#include <hip/hip_runtime.h>
#include <hip/hip_bf16.h>
#include <math.h>

// Problem constants
#define NT 32768
#define HD 96
#define DEG 8
#define NE (NT * DEG)
#define LRELU_ALPHA 0.2f
#define CH 4096              // GRU row-chunk

typedef __attribute__((ext_vector_type(8))) short bf16x8;     // 8 bf16 (4 VGPRs)
typedef __attribute__((ext_vector_type(8))) unsigned short u16x8;
typedef __attribute__((ext_vector_type(4))) float f32x4;

__device__ __forceinline__ unsigned short f2bf(float x) {
    union { float f; unsigned u; } v; v.f = x;
    unsigned r = v.u + 0x7FFFu + ((v.u >> 16) & 1u);   // RNE
    return (unsigned short)(r >> 16);
}

__device__ __forceinline__ void gload_lds16(const void* g, void* l) {
    __builtin_amdgcn_global_load_lds(
        (const __attribute__((address_space(1))) void*)g,
        (__attribute__((address_space(3))) void*)l, 16, 0, 0);
}

// ---------------------------------------------------------------------------
// Pack kernels
// ---------------------------------------------------------------------------

// W [H,768,96] f32 -> T bf16 [768 c][768 f], T[c][f] = W[c/96][f][c%96]
__global__ void packWT(const float* __restrict__ W, unsigned short* __restrict__ T) {
    int idx = blockIdx.x * 256 + threadIdx.x;
    if (idx >= 768 * 768) return;
    int c = idx / 768, f = idx % 768;
    T[idx] = f2bf(W[(size_t)(c / HD) * 768 * HD + (size_t)f * HD + (c % HD)]);
}

// plain f32 -> bf16 convert
__global__ void cvt_bf(const float* __restrict__ X, unsigned short* __restrict__ Y, int n) {
    int i = blockIdx.x * 256 + threadIdx.x;
    if (i < n) Y[i] = f2bf(X[i]);
}

// ---------------------------------------------------------------------------
// bf16 MFMA GEMM: C[M,N] = A[M,K]_f32 @ B + bias,  B given as BT bf16 [N][K].
// 128x128 tile, BK=32, 256 threads (4 waves, 2x2), 16x16x32 MFMA.
// A: reg-staged f32->bf16 into padded LDS (stride 40 bf16 = 80B; reads 2-way,
//    writes bank-uniform). B: global_load_lds w=16 into linear [128][32] with
//    XOR source-preswizzle (slot s holds kword s^((row>>1)&3)); reads 2-way.
// ---------------------------------------------------------------------------
__global__ __launch_bounds__(256, 2) void mgemm_bias(
    const float* __restrict__ A, const unsigned short* __restrict__ BT,
    const float* __restrict__ bias, float* __restrict__ C,
    int M, int N, int K) {
    __shared__ unsigned short Alds[128 * 40];   // 10240 B
    __shared__ unsigned short Blds[128 * 32];   //  8192 B
    const int tid = threadIdx.x;
    const int w = tid >> 6, l = tid & 63;
    const int wr = w >> 1, wc = w & 1;
    const int lrow = l & 15, lk = l >> 4;
    const int bm = blockIdx.y, bn = blockIdx.x;

    // A staging: thread t covers tile-row t>>1, 64B global chunk (t&1)
    const int arow = tid >> 1;
    const int as0 = (tid & 1) * 2;              // first of its 2 LDS slots
    const float* aptr = A + (size_t)(bm * 128 + arow) * K + as0 * 8;

    // B staging: issue q covers slots [q*256, q*256+256); lane's slot = q*256+tid
    const unsigned short* bsrc[2];
    #pragma unroll
    for (int q = 0; q < 2; q++) {
        int idx = q * 256 + tid;
        int br = idx >> 2, bs = idx & 3;
        int kw = bs ^ ((br >> 1) & 3);
        bsrc[q] = BT + (size_t)(bn * 128 + br) * K + kw * 8;
    }

    f32x4 acc[4][4] = {};

    for (int k0 = 0; k0 < K; k0 += 32) {
        __syncthreads();
        // --- stage B (async DMA, wave-uniform LDS base + lane*16) ---
        gload_lds16(bsrc[0] + k0, &Blds[(0 * 256 + w * 64) * 8]);
        gload_lds16(bsrc[1] + k0, &Blds[(1 * 256 + w * 64) * 8]);
        // --- stage A (reg: 4x dwordx4 -> cvt -> 2x ds_write_b128) ---
        float4 a0 = *(const float4*)(aptr + k0);
        float4 a1 = *(const float4*)(aptr + k0 + 4);
        float4 a2 = *(const float4*)(aptr + k0 + 8);
        float4 a3 = *(const float4*)(aptr + k0 + 12);
        u16x8 p0, p1;
        p0[0] = f2bf(a0.x); p0[1] = f2bf(a0.y); p0[2] = f2bf(a0.z); p0[3] = f2bf(a0.w);
        p0[4] = f2bf(a1.x); p0[5] = f2bf(a1.y); p0[6] = f2bf(a1.z); p0[7] = f2bf(a1.w);
        p1[0] = f2bf(a2.x); p1[1] = f2bf(a2.y); p1[2] = f2bf(a2.z); p1[3] = f2bf(a2.w);
        p1[4] = f2bf(a3.x); p1[5] = f2bf(a3.y); p1[6] = f2bf(a3.z); p1[7] = f2bf(a3.w);
        *(u16x8*)(&Alds[arow * 40 + as0 * 8]) = p0;
        *(u16x8*)(&Alds[arow * 40 + as0 * 8 + 8]) = p1;
        __syncthreads();
        // --- fragments + 16 MFMA ---
        bf16x8 af[4], bfv[4];
        #pragma unroll
        for (int i = 0; i < 4; i++) {
            int r = wr * 64 + i * 16 + lrow;
            af[i] = *(const bf16x8*)(&Alds[r * 40 + lk * 8]);
        }
        #pragma unroll
        for (int j = 0; j < 4; j++) {
            int r = wc * 64 + j * 16 + lrow;
            int s = lk ^ ((r >> 1) & 3);
            bfv[j] = *(const bf16x8*)(&Blds[r * 32 + s * 8]);
        }
        #pragma unroll
        for (int i = 0; i < 4; i++)
            #pragma unroll
            for (int j = 0; j < 4; j++)
                acc[i][j] = __builtin_amdgcn_mfma_f32_16x16x32_bf16(af[i], bfv[j], acc[i][j], 0, 0, 0);
    }

    // epilogue: D row = (lane>>4)*4+e, col = lane&15  (guide §3, m89-verified)
    const size_t crow0 = (size_t)bm * 128 + wr * 64;
    const int ccol0 = bn * 128 + wc * 64;
    #pragma unroll
    for (int j = 0; j < 4; j++) {
        int col = ccol0 + j * 16 + lrow;
        float bv = bias[col];
        #pragma unroll
        for (int i = 0; i < 4; i++) {
            size_t row = crow0 + i * 16 + lk * 4;
            #pragma unroll
            for (int e = 0; e < 4; e++)
                C[(row + e) * N + col] = acc[i][j][e] + bv;
        }
    }
}

// ---------------------------------------------------------------------------
// Edge score projections: sc[n*8+h] = sum_d X[n*768 + h*96 + d] * a[h*192 + half*96 + d]
// ---------------------------------------------------------------------------
__global__ __launch_bounds__(256) void escore(
    const float* __restrict__ X, const float* __restrict__ a,
    int half, float* __restrict__ sc) {
    __shared__ float av[768];
    for (int t = threadIdx.x; t < 768; t += 256) {
        int hh = t / HD, d = t % HD;
        av[t] = a[hh * 2 * HD + half * HD + d];
    }
    __syncthreads();
    int idx = blockIdx.x * 256 + threadIdx.x;   // (n,h)
    int row = idx >> 3, hh = idx & 7;
    const float* xp = X + (size_t)row * 768 + hh * HD;
    const float* ap = av + hh * HD;
    float s = 0.f;
    #pragma unroll
    for (int d = 0; d < HD; d++) s += xp[d] * ap[d];
    sc[idx] = s;
}

// ---------------------------------------------------------------------------
// Per-dst-node softmax over 8 contiguous mailbox edges + weighted aggregate.
// ---------------------------------------------------------------------------
__global__ __launch_bounds__(256) void attend_agg(
    const float* __restrict__ Whs, const float* __restrict__ es,
    const float* __restrict__ ed, const float* __restrict__ ab,
    const int* __restrict__ src, const int* __restrict__ dst,
    float* __restrict__ out, float alpha, float beta) {
    int i = blockIdx.x;
    int tid = threadIdx.x;
    __shared__ float att_s[64];
    __shared__ int src_s[8];
    __shared__ int dnode_s;
    if (tid < 8) src_s[tid] = src[i * 8 + tid];
    if (tid == 0) dnode_s = dst[i * 8];
    __syncthreads();
    int dnode = dnode_s;
    if (tid < 64) {
        int hh = tid >> 3;
        int j  = tid & 7;
        float e = es[(size_t)src_s[j] * 8 + hh] + ed[(size_t)dnode * 8 + hh] + ab[hh];
        e = e > 0.f ? e : LRELU_ALPHA * e;
        float m = e;
        #pragma unroll
        for (int o = 1; o < 8; o <<= 1) m = fmaxf(m, __shfl_xor(m, o, 64));
        float ex = expf(e - m);
        float s = ex;
        #pragma unroll
        for (int o = 1; o < 8; o <<= 1) s += __shfl_xor(s, o, 64);
        att_s[tid] = ex / s;
    }
    __syncthreads();
    #pragma unroll
    for (int u = 0; u < 3; u++) {
        int c = tid + u * 256;
        int hh = c / HD;
        float acc = 0.f;
        #pragma unroll
        for (int j = 0; j < 8; j++)
            acc += att_s[hh * 8 + j] * Whs[(size_t)src_s[j] * 768 + c];
        float r = alpha * acc;
        if (beta != 0.f) r += beta * out[(size_t)dnode * 768 + c];
        out[(size_t)dnode * 768 + c] = r;
    }
}

// ---------------------------------------------------------------------------
// GRU elementwise tail for one row-chunk.
// ---------------------------------------------------------------------------
__global__ __launch_bounds__(256) void gru_elem(
    const float* __restrict__ gi, const float* __restrict__ gh,
    const float* __restrict__ hid, float* __restrict__ out) {
    int idx = blockIdx.x * 256 + threadIdx.x;
    int nrow = idx / 768, c = idx % 768;
    const float* gip = gi + (size_t)nrow * 2304;
    const float* ghp = gh + (size_t)nrow * 2304;
    float ir  = gip[c],        hr = ghp[c];
    float iz  = gip[768 + c],  hz = ghp[768 + c];
    float in_ = gip[1536 + c], hn = ghp[1536 + c];
    float r = 1.f / (1.f + expf(-(ir + hr)));
    float z = 1.f / (1.f + expf(-(iz + hz)));
    float cand = tanhf(in_ + r * hn);
    float hv = hid[idx];
    out[idx] = (1.f - z) * cand + z * hv;
}

// ---------------------------------------------------------------------------
// Launch. ws (floats): X[SZ] | Hd[SZ] | GI[CH*2304] | GH[CH*2304] |
//   bf16: W2gT(768*768) W2xT(768*768) WihB(2304*768) WhhB(2304*768) |
//   f32: ES ED ESI EDI (NT*8 each).  Total ~291 MB. P (proj scratch) = d_out.
// ---------------------------------------------------------------------------
extern "C" void kernel_launch(void* const* d_in, const int* in_sizes, int n_in,
                              void* d_out, int out_size, void* d_ws, size_t ws_size,
                              hipStream_t stream) {
    const float* h    = (const float*)d_in[0];
    const float* hbc  = (const float*)d_in[1];
    const float* hbs  = (const float*)d_in[2];
    const float* Wg   = (const float*)d_in[3];
    const float* bg   = (const float*)d_in[4];
    const float* ag   = (const float*)d_in[5];
    const float* agb  = (const float*)d_in[6];
    const float* Wx   = (const float*)d_in[7];
    const float* bx   = (const float*)d_in[8];
    const float* ax   = (const float*)d_in[9];
    const float* axb  = (const float*)d_in[10];
    const float* Wih  = (const float*)d_in[11];
    const float* Whh  = (const float*)d_in[12];
    const float* bih  = (const float*)d_in[13];
    const float* bhh  = (const float*)d_in[14];
    const int* i_src  = (const int*)d_in[15];
    const int* i_dst  = (const int*)d_in[16];
    const int* c_src  = (const int*)d_in[17];
    const int* c_dst  = (const int*)d_in[18];
    const int* s_src  = (const int*)d_in[19];
    const int* s_dst  = (const int*)d_in[20];
    float* out = (float*)d_out;
    float* ws  = (float*)d_ws;

    const size_t SZ = (size_t)NT * 768;
    float* X   = ws;
    float* Hd  = ws + SZ;
    float* GI  = ws + 2 * SZ;
    float* GH  = GI + (size_t)CH * 2304;
    float* P   = out;                       // projection scratch (reuses d_out)
    unsigned short* W2gT = (unsigned short*)(GH + (size_t)CH * 2304);
    unsigned short* W2xT = W2gT + 768 * 768;
    unsigned short* WihB = W2xT + 768 * 768;
    unsigned short* WhhB = WihB + 2304 * 768;
    float* ES  = (float*)(WhhB + 2304 * 768);
    float* ED  = ES + NE;
    float* ESI = ED + NE;
    float* EDI = ESI + NE;

    dim3 blk(256);
    packWT<<<(768 * 768 + 255) / 256, blk, 0, stream>>>(Wg, W2gT);
    packWT<<<(768 * 768 + 255) / 256, blk, 0, stream>>>(Wx, W2xT);
    cvt_bf<<<(2304 * 768 + 255) / 256, blk, 0, stream>>>(Wih, WihB, 2304 * 768);
    cvt_bf<<<(2304 * 768 + 255) / 256, blk, 0, stream>>>(Whh, WhhB, 2304 * 768);

    dim3 g768(6, NT / 128);      // (6, 256)

    // 1) Wh = h @ Wg + bg -> P
    mgemm_bias<<<g768, blk, 0, stream>>>(h, W2gT, bg, P, NT, 768, 768);
    // 2) intra scores + attend -> X
    escore<<<NE / 256, blk, 0, stream>>>(P, ag, 0, ESI);
    escore<<<NE / 256, blk, 0, stream>>>(P, ag, 1, EDI);
    attend_agg<<<NT, blk, 0, stream>>>(P, ESI, EDI, agb, i_src, i_dst, X, 1.f, 0.f);
    // 3) Wx_d = X @ Wx + bx -> P ; dst scores
    mgemm_bias<<<g768, blk, 0, stream>>>(X, W2xT, bx, P, NT, 768, 768);
    escore<<<NE / 256, blk, 0, stream>>>(P, ax, 1, ED);
    // 4) counter branch
    mgemm_bias<<<g768, blk, 0, stream>>>(hbc, W2xT, bx, P, NT, 768, 768);
    escore<<<NE / 256, blk, 0, stream>>>(P, ax, 0, ES);
    attend_agg<<<NT, blk, 0, stream>>>(P, ES, ED, axb, c_src, c_dst, Hd, 0.5f, 0.f);
    // 5) support branch
    mgemm_bias<<<g768, blk, 0, stream>>>(hbs, W2xT, bx, P, NT, 768, 768);
    escore<<<NE / 256, blk, 0, stream>>>(P, ax, 0, ES);
    attend_agg<<<NT, blk, 0, stream>>>(P, ES, ED, axb, s_src, s_dst, Hd, 0.5f, 1.f);

    // 6) GRU, row-chunked
    dim3 gch(2304 / 128, CH / 128);   // (18, 32)
    for (int c0 = 0; c0 < NT; c0 += CH) {
        const float* Xc = X  + (size_t)c0 * 768;
        const float* Hc = Hd + (size_t)c0 * 768;
        mgemm_bias<<<gch, blk, 0, stream>>>(Xc, WihB, bih, GI, CH, 2304, 768);
        mgemm_bias<<<gch, blk, 0, stream>>>(Hc, WhhB, bhh, GH, CH, 2304, 768);
        gru_elem<<<(CH * 768) / 256, blk, 0, stream>>>(GI, GH, Hc, out + (size_t)c0 * 768);
    }
}

// Round 5
// 1195.662 us; speedup vs baseline: 19.5688x; 1.5361x over previous
//
#include <hip/hip_runtime.h>
#include <hip/hip_bf16.h>
#include <math.h>

// Problem constants
#define NT 32768
#define HD 96
#define DEG 8
#define NE (NT * DEG)
#define LRELU_ALPHA 0.2f
#define CH 8192              // GRU row-chunk

typedef __attribute__((ext_vector_type(8))) short bf16x8;     // 8 bf16 (4 VGPRs)
typedef __attribute__((ext_vector_type(8))) unsigned short u16x8;
typedef __attribute__((ext_vector_type(4))) float f32x4;

__device__ __forceinline__ unsigned short f2bf(float x) {
    union { float f; unsigned u; } v; v.f = x;
    unsigned r = v.u + 0x7FFFu + ((v.u >> 16) & 1u);   // RNE
    return (unsigned short)(r >> 16);
}
__device__ __forceinline__ float bf2f(unsigned short u) {
    union { unsigned u; float f; } v; v.u = ((unsigned)u) << 16; return v.f;
}

__device__ __forceinline__ void gload_lds16(const void* g, void* l) {
    __builtin_amdgcn_global_load_lds(
        (const __attribute__((address_space(1))) void*)g,
        (__attribute__((address_space(3))) void*)l, 16, 0, 0);
}

// ---------------------------------------------------------------------------
// Pack kernels
// ---------------------------------------------------------------------------

// W [H,768,96] f32 -> T bf16 [768 c][768 f], T[c][f] = W[c/96][f][c%96]
__global__ void packWT(const float* __restrict__ W, unsigned short* __restrict__ T) {
    int idx = blockIdx.x * 256 + threadIdx.x;
    if (idx >= 768 * 768) return;
    int c = idx / 768, f = idx % 768;
    T[idx] = f2bf(W[(size_t)(c / HD) * 768 * HD + (size_t)f * HD + (c % HD)]);
}

// plain f32 -> bf16 convert
__global__ void cvt_bf(const float* __restrict__ X, unsigned short* __restrict__ Y, int n) {
    int i = blockIdx.x * 256 + threadIdx.x;
    if (i < n) Y[i] = f2bf(X[i]);
}

// ---------------------------------------------------------------------------
// MFMA GEMM, f32 A variant: C_bf16[M,N] = A_f32[M,K] @ BT_bf16 + bias.
// 128x128 tile, BK=32, 256 thr (4 waves 2x2), 16x16x32 MFMA. (round-4 proven;
// epilogue now writes bf16)
// ---------------------------------------------------------------------------
__global__ __launch_bounds__(256, 2) void mgemm_fb(
    const float* __restrict__ A, const unsigned short* __restrict__ BT,
    const float* __restrict__ bias, unsigned short* __restrict__ C,
    int M, int N, int K) {
    __shared__ unsigned short Alds[128 * 40];   // padded stride 40 (80B)
    __shared__ unsigned short Blds[128 * 32];
    const int tid = threadIdx.x;
    const int w = tid >> 6, l = tid & 63;
    const int wr = w >> 1, wc = w & 1;
    const int lrow = l & 15, lk = l >> 4;
    const int bm = blockIdx.y, bn = blockIdx.x;

    const int arow = tid >> 1;
    const int as0 = (tid & 1) * 2;
    const float* aptr = A + (size_t)(bm * 128 + arow) * K + as0 * 8;

    const unsigned short* bsrc[2];
    #pragma unroll
    for (int q = 0; q < 2; q++) {
        int idx = q * 256 + tid;
        int br = idx >> 2, bs = idx & 3;
        int kw = bs ^ ((br >> 1) & 3);
        bsrc[q] = BT + (size_t)(bn * 128 + br) * K + kw * 8;
    }

    f32x4 acc[4][4] = {};

    for (int k0 = 0; k0 < K; k0 += 32) {
        __syncthreads();
        gload_lds16(bsrc[0] + k0, &Blds[(0 * 256 + w * 64) * 8]);
        gload_lds16(bsrc[1] + k0, &Blds[(1 * 256 + w * 64) * 8]);
        float4 a0 = *(const float4*)(aptr + k0);
        float4 a1 = *(const float4*)(aptr + k0 + 4);
        float4 a2 = *(const float4*)(aptr + k0 + 8);
        float4 a3 = *(const float4*)(aptr + k0 + 12);
        u16x8 p0, p1;
        p0[0] = f2bf(a0.x); p0[1] = f2bf(a0.y); p0[2] = f2bf(a0.z); p0[3] = f2bf(a0.w);
        p0[4] = f2bf(a1.x); p0[5] = f2bf(a1.y); p0[6] = f2bf(a1.z); p0[7] = f2bf(a1.w);
        p1[0] = f2bf(a2.x); p1[1] = f2bf(a2.y); p1[2] = f2bf(a2.z); p1[3] = f2bf(a2.w);
        p1[4] = f2bf(a3.x); p1[5] = f2bf(a3.y); p1[6] = f2bf(a3.z); p1[7] = f2bf(a3.w);
        *(u16x8*)(&Alds[arow * 40 + as0 * 8]) = p0;
        *(u16x8*)(&Alds[arow * 40 + as0 * 8 + 8]) = p1;
        __syncthreads();
        bf16x8 af[4], bfv[4];
        #pragma unroll
        for (int i = 0; i < 4; i++) {
            int r = wr * 64 + i * 16 + lrow;
            af[i] = *(const bf16x8*)(&Alds[r * 40 + lk * 8]);
        }
        #pragma unroll
        for (int j = 0; j < 4; j++) {
            int r = wc * 64 + j * 16 + lrow;
            int s = lk ^ ((r >> 1) & 3);
            bfv[j] = *(const bf16x8*)(&Blds[r * 32 + s * 8]);
        }
        #pragma unroll
        for (int i = 0; i < 4; i++)
            #pragma unroll
            for (int j = 0; j < 4; j++)
                acc[i][j] = __builtin_amdgcn_mfma_f32_16x16x32_bf16(af[i], bfv[j], acc[i][j], 0, 0, 0);
    }

    const size_t crow0 = (size_t)bm * 128 + wr * 64;
    const int ccol0 = bn * 128 + wc * 64;
    #pragma unroll
    for (int j = 0; j < 4; j++) {
        int col = ccol0 + j * 16 + lrow;
        float bv = bias[col];
        #pragma unroll
        for (int i = 0; i < 4; i++) {
            size_t row = crow0 + i * 16 + lk * 4;
            #pragma unroll
            for (int e = 0; e < 4; e++)
                C[(row + e) * N + col] = f2bf(acc[i][j][e] + bv);
        }
    }
}

// ---------------------------------------------------------------------------
// MFMA GEMM, bf16 A variant: both A and BT staged via global_load_lds w=16
// with XOR source-preswizzle (slot s holds k-word s^((row>>1)&3)).
// ---------------------------------------------------------------------------
__global__ __launch_bounds__(256, 2) void mgemm_bb(
    const unsigned short* __restrict__ A, const unsigned short* __restrict__ BT,
    const float* __restrict__ bias, unsigned short* __restrict__ C,
    int M, int N, int K) {
    __shared__ unsigned short Alds[128 * 32];
    __shared__ unsigned short Blds[128 * 32];
    const int tid = threadIdx.x;
    const int w = tid >> 6, l = tid & 63;
    const int wr = w >> 1, wc = w & 1;
    const int lrow = l & 15, lk = l >> 4;
    const int bm = blockIdx.y, bn = blockIdx.x;

    const unsigned short* asrc[2];
    const unsigned short* bsrc[2];
    #pragma unroll
    for (int q = 0; q < 2; q++) {
        int idx = q * 256 + tid;
        int r = idx >> 2, s = idx & 3;
        int kw = s ^ ((r >> 1) & 3);
        asrc[q] = A  + (size_t)(bm * 128 + r) * K + kw * 8;
        bsrc[q] = BT + (size_t)(bn * 128 + r) * K + kw * 8;
    }

    f32x4 acc[4][4] = {};

    for (int k0 = 0; k0 < K; k0 += 32) {
        __syncthreads();
        gload_lds16(asrc[0] + k0, &Alds[(0 * 256 + w * 64) * 8]);
        gload_lds16(asrc[1] + k0, &Alds[(1 * 256 + w * 64) * 8]);
        gload_lds16(bsrc[0] + k0, &Blds[(0 * 256 + w * 64) * 8]);
        gload_lds16(bsrc[1] + k0, &Blds[(1 * 256 + w * 64) * 8]);
        __syncthreads();
        bf16x8 af[4], bfv[4];
        #pragma unroll
        for (int i = 0; i < 4; i++) {
            int r = wr * 64 + i * 16 + lrow;
            int s = lk ^ ((r >> 1) & 3);
            af[i] = *(const bf16x8*)(&Alds[r * 32 + s * 8]);
        }
        #pragma unroll
        for (int j = 0; j < 4; j++) {
            int r = wc * 64 + j * 16 + lrow;
            int s = lk ^ ((r >> 1) & 3);
            bfv[j] = *(const bf16x8*)(&Blds[r * 32 + s * 8]);
        }
        #pragma unroll
        for (int i = 0; i < 4; i++)
            #pragma unroll
            for (int j = 0; j < 4; j++)
                acc[i][j] = __builtin_amdgcn_mfma_f32_16x16x32_bf16(af[i], bfv[j], acc[i][j], 0, 0, 0);
    }

    const size_t crow0 = (size_t)bm * 128 + wr * 64;
    const int ccol0 = bn * 128 + wc * 64;
    #pragma unroll
    for (int j = 0; j < 4; j++) {
        int col = ccol0 + j * 16 + lrow;
        float bv = bias[col];
        #pragma unroll
        for (int i = 0; i < 4; i++) {
            size_t row = crow0 + i * 16 + lk * 4;
            #pragma unroll
            for (int e = 0; e < 4; e++)
                C[(row + e) * N + col] = f2bf(acc[i][j][e] + bv);
        }
    }
}

// ---------------------------------------------------------------------------
// Edge score: sc[n*8+h] = sum_d X_bf16[n*768 + h*96 + d] * a[h*192 + half*96 + d]
// ---------------------------------------------------------------------------
__global__ __launch_bounds__(256) void escore(
    const unsigned short* __restrict__ X, const float* __restrict__ a,
    int half, float* __restrict__ sc) {
    __shared__ float av[768];
    for (int t = threadIdx.x; t < 768; t += 256) {
        int hh = t / HD, d = t % HD;
        av[t] = a[hh * 2 * HD + half * HD + d];
    }
    __syncthreads();
    int idx = blockIdx.x * 256 + threadIdx.x;   // (n,h)
    int row = idx >> 3, hh = idx & 7;
    const unsigned short* xp = X + (size_t)row * 768 + hh * HD;
    const float* ap = av + hh * HD;
    float s = 0.f;
    #pragma unroll
    for (int q = 0; q < 12; q++) {
        u16x8 v = *(const u16x8*)(xp + q * 8);
        #pragma unroll
        for (int e = 0; e < 8; e++) s += bf2f(v[e]) * ap[q * 8 + e];
    }
    sc[idx] = s;
}

// ---------------------------------------------------------------------------
// Per-dst softmax over 8 contiguous edges + weighted aggregate (bf16 table).
// ---------------------------------------------------------------------------
__global__ __launch_bounds__(256) void attend_agg(
    const unsigned short* __restrict__ Whs, const float* __restrict__ es,
    const float* __restrict__ ed, const float* __restrict__ ab,
    const int* __restrict__ src, const int* __restrict__ dst,
    unsigned short* __restrict__ out, float alpha, float beta) {
    int i = blockIdx.x;
    int tid = threadIdx.x;
    __shared__ float att_s[64];
    __shared__ int src_s[8];
    __shared__ int dnode_s;
    if (tid < 8) src_s[tid] = src[i * 8 + tid];
    if (tid == 0) dnode_s = dst[i * 8];
    __syncthreads();
    int dnode = dnode_s;
    if (tid < 64) {
        int hh = tid >> 3;
        int j  = tid & 7;
        float e = es[(size_t)src_s[j] * 8 + hh] + ed[(size_t)dnode * 8 + hh] + ab[hh];
        e = e > 0.f ? e : LRELU_ALPHA * e;
        float m = e;
        #pragma unroll
        for (int o = 1; o < 8; o <<= 1) m = fmaxf(m, __shfl_xor(m, o, 64));
        float ex = expf(e - m);
        float s = ex;
        #pragma unroll
        for (int o = 1; o < 8; o <<= 1) s += __shfl_xor(s, o, 64);
        att_s[tid] = ex / s;
    }
    __syncthreads();
    #pragma unroll
    for (int u = 0; u < 3; u++) {
        int c = tid + u * 256;
        int hh = c / HD;
        float acc = 0.f;
        #pragma unroll
        for (int j = 0; j < 8; j++)
            acc += att_s[hh * 8 + j] * bf2f(Whs[(size_t)src_s[j] * 768 + c]);
        float r = alpha * acc;
        if (beta != 0.f) r += beta * bf2f(out[(size_t)dnode * 768 + c]);
        out[(size_t)dnode * 768 + c] = f2bf(r);
    }
}

// ---------------------------------------------------------------------------
// GRU elementwise tail (bf16 gi/gh/hid, f32 out), 8 cols/thread.
// ---------------------------------------------------------------------------
__global__ __launch_bounds__(256) void gru_elem(
    const unsigned short* __restrict__ gi, const unsigned short* __restrict__ gh,
    const unsigned short* __restrict__ hid, float* __restrict__ out) {
    int idx = blockIdx.x * 256 + threadIdx.x;   // over rows*96
    int nrow = idx / 96, c8 = (idx % 96) * 8;
    const unsigned short* gip = gi + (size_t)nrow * 2304 + c8;
    const unsigned short* ghp = gh + (size_t)nrow * 2304 + c8;
    u16x8 vir = *(const u16x8*)(gip);
    u16x8 viz = *(const u16x8*)(gip + 768);
    u16x8 vin = *(const u16x8*)(gip + 1536);
    u16x8 vhr = *(const u16x8*)(ghp);
    u16x8 vhz = *(const u16x8*)(ghp + 768);
    u16x8 vhn = *(const u16x8*)(ghp + 1536);
    u16x8 vh  = *(const u16x8*)(hid + (size_t)nrow * 768 + c8);
    float res[8];
    #pragma unroll
    for (int e = 0; e < 8; e++) {
        float r = 1.f / (1.f + expf(-(bf2f(vir[e]) + bf2f(vhr[e]))));
        float z = 1.f / (1.f + expf(-(bf2f(viz[e]) + bf2f(vhz[e]))));
        float cand = tanhf(bf2f(vin[e]) + r * bf2f(vhn[e]));
        res[e] = (1.f - z) * cand + z * bf2f(vh[e]);
    }
    float* op = out + (size_t)nrow * 768 + c8;
    *(float4*)(op)     = make_float4(res[0], res[1], res[2], res[3]);
    *(float4*)(op + 4) = make_float4(res[4], res[5], res[6], res[7]);
}

// ---------------------------------------------------------------------------
// Launch. ws: Xb[NT*768 bf16] | Hdb[NT*768 bf16] | GIb[CH*2304 bf16] |
//   GHb[CH*2304 bf16] | W2gT W2xT WihB WhhB (bf16) | ES ED ESI EDI (f32).
// P (projection scratch, bf16 [NT,768]) lives in d_out.  Total ws ~190 MB.
// ---------------------------------------------------------------------------
extern "C" void kernel_launch(void* const* d_in, const int* in_sizes, int n_in,
                              void* d_out, int out_size, void* d_ws, size_t ws_size,
                              hipStream_t stream) {
    const float* h    = (const float*)d_in[0];
    const float* hbc  = (const float*)d_in[1];
    const float* hbs  = (const float*)d_in[2];
    const float* Wg   = (const float*)d_in[3];
    const float* bg   = (const float*)d_in[4];
    const float* ag   = (const float*)d_in[5];
    const float* agb  = (const float*)d_in[6];
    const float* Wx   = (const float*)d_in[7];
    const float* bx   = (const float*)d_in[8];
    const float* ax   = (const float*)d_in[9];
    const float* axb  = (const float*)d_in[10];
    const float* Wih  = (const float*)d_in[11];
    const float* Whh  = (const float*)d_in[12];
    const float* bih  = (const float*)d_in[13];
    const float* bhh  = (const float*)d_in[14];
    const int* i_src  = (const int*)d_in[15];
    const int* i_dst  = (const int*)d_in[16];
    const int* c_src  = (const int*)d_in[17];
    const int* c_dst  = (const int*)d_in[18];
    const int* s_src  = (const int*)d_in[19];
    const int* s_dst  = (const int*)d_in[20];
    float* out = (float*)d_out;

    const size_t SZ = (size_t)NT * 768;
    unsigned short* Xb  = (unsigned short*)d_ws;
    unsigned short* Hdb = Xb + SZ;
    unsigned short* GIb = Hdb + SZ;
    unsigned short* GHb = GIb + (size_t)CH * 2304;
    unsigned short* W2gT = GHb + (size_t)CH * 2304;
    unsigned short* W2xT = W2gT + 768 * 768;
    unsigned short* WihB = W2xT + 768 * 768;
    unsigned short* WhhB = WihB + 2304 * 768;
    float* ES  = (float*)(WhhB + 2304 * 768);
    float* ED  = ES + NE;
    float* ESI = ED + NE;
    float* EDI = ESI + NE;
    unsigned short* Pb = (unsigned short*)d_out;   // bf16 scratch in d_out

    dim3 blk(256);
    packWT<<<(768 * 768 + 255) / 256, blk, 0, stream>>>(Wg, W2gT);
    packWT<<<(768 * 768 + 255) / 256, blk, 0, stream>>>(Wx, W2xT);
    cvt_bf<<<(2304 * 768 + 255) / 256, blk, 0, stream>>>(Wih, WihB, 2304 * 768);
    cvt_bf<<<(2304 * 768 + 255) / 256, blk, 0, stream>>>(Whh, WhhB, 2304 * 768);

    dim3 g768(6, NT / 128);      // (6, 256)

    // 1) Wh = h @ Wg + bg -> Pb
    mgemm_fb<<<g768, blk, 0, stream>>>(h, W2gT, bg, Pb, NT, 768, 768);
    // 2) intra scores + attend -> Xb
    escore<<<NE / 256, blk, 0, stream>>>(Pb, ag, 0, ESI);
    escore<<<NE / 256, blk, 0, stream>>>(Pb, ag, 1, EDI);
    attend_agg<<<NT, blk, 0, stream>>>(Pb, ESI, EDI, agb, i_src, i_dst, Xb, 1.f, 0.f);
    // 3) Wx_d = X @ Wx + bx -> Pb ; dst scores
    mgemm_bb<<<g768, blk, 0, stream>>>(Xb, W2xT, bx, Pb, NT, 768, 768);
    escore<<<NE / 256, blk, 0, stream>>>(Pb, ax, 1, ED);
    // 4) counter branch
    mgemm_fb<<<g768, blk, 0, stream>>>(hbc, W2xT, bx, Pb, NT, 768, 768);
    escore<<<NE / 256, blk, 0, stream>>>(Pb, ax, 0, ES);
    attend_agg<<<NT, blk, 0, stream>>>(Pb, ES, ED, axb, c_src, c_dst, Hdb, 0.5f, 0.f);
    // 5) support branch
    mgemm_fb<<<g768, blk, 0, stream>>>(hbs, W2xT, bx, Pb, NT, 768, 768);
    escore<<<NE / 256, blk, 0, stream>>>(Pb, ax, 0, ES);
    attend_agg<<<NT, blk, 0, stream>>>(Pb, ES, ED, axb, s_src, s_dst, Hdb, 0.5f, 1.f);

    // 6) GRU, row-chunked
    dim3 gch(2304 / 128, CH / 128);   // (18, 64)
    for (int c0 = 0; c0 < NT; c0 += CH) {
        mgemm_bb<<<gch, blk, 0, stream>>>(Xb  + (size_t)c0 * 768, WihB, bih, GIb, CH, 2304, 768);
        mgemm_bb<<<gch, blk, 0, stream>>>(Hdb + (size_t)c0 * 768, WhhB, bhh, GHb, CH, 2304, 768);
        gru_elem<<<(CH * 96) / 256, blk, 0, stream>>>(GIb, GHb, Hdb + (size_t)c0 * 768, out + (size_t)c0 * 768);
    }
}

// Round 6
// 1030.622 us; speedup vs baseline: 22.7025x; 1.1601x over previous
//
#include <hip/hip_runtime.h>
#include <hip/hip_bf16.h>
#include <math.h>

// Problem constants
#define NT 32768
#define HD 96
#define DEG 8
#define NE (NT * DEG)
#define LRELU_ALPHA 0.2f
#define CH 8192              // GRU row-chunk

typedef __attribute__((ext_vector_type(8))) short bf16x8;     // 8 bf16 (4 VGPRs)
typedef __attribute__((ext_vector_type(8))) unsigned short u16x8;
typedef __attribute__((ext_vector_type(4))) unsigned short u16x4;
typedef __attribute__((ext_vector_type(4))) float f32x4;

__device__ __forceinline__ unsigned short f2bf(float x) {
    union { float f; unsigned u; } v; v.f = x;
    unsigned r = v.u + 0x7FFFu + ((v.u >> 16) & 1u);   // RNE
    return (unsigned short)(r >> 16);
}
__device__ __forceinline__ float bf2f(unsigned short u) {
    union { unsigned u; float f; } v; v.u = ((unsigned)u) << 16; return v.f;
}

__device__ __forceinline__ void gload_lds16(const void* g, void* l) {
    __builtin_amdgcn_global_load_lds(
        (const __attribute__((address_space(1))) void*)g,
        (__attribute__((address_space(3))) void*)l, 16, 0, 0);
}

// ---------------------------------------------------------------------------
// Pack kernels
// ---------------------------------------------------------------------------

// W [H,768,96] f32 -> T bf16 [768 c][768 f], T[c][f] = W[c/96][f][c%96]
__global__ void packWT(const float* __restrict__ W, unsigned short* __restrict__ T) {
    int idx = blockIdx.x * 256 + threadIdx.x;
    if (idx >= 768 * 768) return;
    int c = idx / 768, f = idx % 768;
    T[idx] = f2bf(W[(size_t)(c / HD) * 768 * HD + (size_t)f * HD + (c % HD)]);
}

// vectorized f32 -> bf16 (8 elems/thread); n8 = n/8
__global__ void cvt_bf8(const float* __restrict__ X, unsigned short* __restrict__ Y, int n8) {
    int i = blockIdx.x * 256 + threadIdx.x;
    if (i >= n8) return;
    float4 a = ((const float4*)X)[2 * i];
    float4 b = ((const float4*)X)[2 * i + 1];
    u16x8 p;
    p[0] = f2bf(a.x); p[1] = f2bf(a.y); p[2] = f2bf(a.z); p[3] = f2bf(a.w);
    p[4] = f2bf(b.x); p[5] = f2bf(b.y); p[6] = f2bf(b.z); p[7] = f2bf(b.w);
    ((u16x8*)Y)[i] = p;
}

// ---------------------------------------------------------------------------
// MFMA GEMM, bf16 A and BT, both staged via global_load_lds w=16 with XOR
// source-preswizzle (slot s holds k-word s^((row>>1)&3)).  128x128 tile,
// BK=32, 256 thr (4 waves 2x2), 16x16x32 MFMA.  XCD-aware tile swizzle (T1).
// ---------------------------------------------------------------------------
__global__ __launch_bounds__(256, 2) void mgemm_bb(
    const unsigned short* __restrict__ A, const unsigned short* __restrict__ BT,
    const float* __restrict__ bias, unsigned short* __restrict__ C,
    int M, int N, int K) {
    __shared__ unsigned short Alds[128 * 32];
    __shared__ unsigned short Blds[128 * 32];
    const int tid = threadIdx.x;
    const int w = tid >> 6, l = tid & 63;
    const int wr = w >> 1, wc = w & 1;
    const int lrow = l & 15, lk = l >> 4;

    // XCD-aware swizzle: consecutive tiles on one XCD share an A panel.
    const int nx = gridDim.x;
    const int nwg = nx * gridDim.y;
    int lin = blockIdx.y * nx + blockIdx.x;
    if ((nwg & 7) == 0) lin = (lin & 7) * (nwg >> 3) + (lin >> 3);
    const int bm = lin / nx, bn = lin % nx;

    const unsigned short* asrc[2];
    const unsigned short* bsrc[2];
    #pragma unroll
    for (int q = 0; q < 2; q++) {
        int idx = q * 256 + tid;
        int r = idx >> 2, s = idx & 3;
        int kw = s ^ ((r >> 1) & 3);
        asrc[q] = A  + (size_t)(bm * 128 + r) * K + kw * 8;
        bsrc[q] = BT + (size_t)(bn * 128 + r) * K + kw * 8;
    }

    f32x4 acc[4][4] = {};

    for (int k0 = 0; k0 < K; k0 += 32) {
        __syncthreads();
        gload_lds16(asrc[0] + k0, &Alds[(0 * 256 + w * 64) * 8]);
        gload_lds16(asrc[1] + k0, &Alds[(1 * 256 + w * 64) * 8]);
        gload_lds16(bsrc[0] + k0, &Blds[(0 * 256 + w * 64) * 8]);
        gload_lds16(bsrc[1] + k0, &Blds[(1 * 256 + w * 64) * 8]);
        __syncthreads();
        bf16x8 af[4], bfv[4];
        #pragma unroll
        for (int i = 0; i < 4; i++) {
            int r = wr * 64 + i * 16 + lrow;
            int s = lk ^ ((r >> 1) & 3);
            af[i] = *(const bf16x8*)(&Alds[r * 32 + s * 8]);
        }
        #pragma unroll
        for (int j = 0; j < 4; j++) {
            int r = wc * 64 + j * 16 + lrow;
            int s = lk ^ ((r >> 1) & 3);
            bfv[j] = *(const bf16x8*)(&Blds[r * 32 + s * 8]);
        }
        #pragma unroll
        for (int i = 0; i < 4; i++)
            #pragma unroll
            for (int j = 0; j < 4; j++)
                acc[i][j] = __builtin_amdgcn_mfma_f32_16x16x32_bf16(af[i], bfv[j], acc[i][j], 0, 0, 0);
    }

    const size_t crow0 = (size_t)bm * 128 + wr * 64;
    const int ccol0 = bn * 128 + wc * 64;
    #pragma unroll
    for (int j = 0; j < 4; j++) {
        int col = ccol0 + j * 16 + lrow;
        float bv = bias[col];
        #pragma unroll
        for (int i = 0; i < 4; i++) {
            size_t row = crow0 + i * 16 + lk * 4;
            #pragma unroll
            for (int e = 0; e < 4; e++)
                C[(row + e) * N + col] = f2bf(acc[i][j][e] + bv);
        }
    }
}

// ---------------------------------------------------------------------------
// Edge score: sc[n*8+h] = sum_d X_bf16[n*768 + h*96 + d] * a[h*192 + half*96 + d]
// ---------------------------------------------------------------------------
__global__ __launch_bounds__(256) void escore(
    const unsigned short* __restrict__ X, const float* __restrict__ a,
    int half, float* __restrict__ sc) {
    __shared__ float av[768];
    for (int t = threadIdx.x; t < 768; t += 256) {
        int hh = t / HD, d = t % HD;
        av[t] = a[hh * 2 * HD + half * HD + d];
    }
    __syncthreads();
    int idx = blockIdx.x * 256 + threadIdx.x;   // (n,h)
    int row = idx >> 3, hh = idx & 7;
    const unsigned short* xp = X + (size_t)row * 768 + hh * HD;
    const float* ap = av + hh * HD;
    float s = 0.f;
    #pragma unroll
    for (int q = 0; q < 12; q++) {
        u16x8 v = *(const u16x8*)(xp + q * 8);
        #pragma unroll
        for (int e = 0; e < 8; e++) s += bf2f(v[e]) * ap[q * 8 + e];
    }
    sc[idx] = s;
}

// ---------------------------------------------------------------------------
// Per-dst softmax + aggregate, one WAVE per dst segment (4 segs/block).
// att fully in-register: lane h*8+j holds edge (h,j). Aggregation: lane l
// covers cols 4*l + 256*u (u=0..2), u16x4 vector gathers.
// ---------------------------------------------------------------------------
__global__ __launch_bounds__(256) void attend_agg(
    const unsigned short* __restrict__ Whs, const float* __restrict__ es,
    const float* __restrict__ ed, const float* __restrict__ ab,
    const int* __restrict__ src, const int* __restrict__ dst,
    unsigned short* __restrict__ out, float alpha, float beta) {
    const int wv = threadIdx.x >> 6, l = threadIdx.x & 63;
    const int seg = blockIdx.x * 4 + wv;
    const int hh = l >> 3, j = l & 7;
    int sj = src[seg * 8 + j];                 // lane l holds src id for edge j
    int dnode = dst[seg * 8];
    float e = es[(size_t)sj * 8 + hh] + ed[(size_t)dnode * 8 + hh] + ab[hh];
    e = e > 0.f ? e : LRELU_ALPHA * e;
    float m = e;
    #pragma unroll
    for (int o = 1; o < 8; o <<= 1) m = fmaxf(m, __shfl_xor(m, o, 64));
    float ex = expf(e - m);
    float s = ex;
    #pragma unroll
    for (int o = 1; o < 8; o <<= 1) s += __shfl_xor(s, o, 64);
    float att = ex / s;                        // lane h*8+j

    #pragma unroll
    for (int u = 0; u < 3; u++) {
        int c = 4 * l + 256 * u;               // col group (4 cols, head-aligned)
        int h = c / HD;
        float acc0 = 0.f, acc1 = 0.f, acc2 = 0.f, acc3 = 0.f;
        #pragma unroll
        for (int j2 = 0; j2 < 8; j2++) {
            float a = __shfl(att, h * 8 + j2, 64);
            int sid = __shfl(sj, j2, 64);
            u16x4 v = *(const u16x4*)(Whs + (size_t)sid * 768 + c);
            acc0 += a * bf2f(v[0]); acc1 += a * bf2f(v[1]);
            acc2 += a * bf2f(v[2]); acc3 += a * bf2f(v[3]);
        }
        u16x4 r;
        unsigned short* op = out + (size_t)dnode * 768 + c;
        if (beta != 0.f) {
            u16x4 pv = *(const u16x4*)op;
            r[0] = f2bf(alpha * acc0 + beta * bf2f(pv[0]));
            r[1] = f2bf(alpha * acc1 + beta * bf2f(pv[1]));
            r[2] = f2bf(alpha * acc2 + beta * bf2f(pv[2]));
            r[3] = f2bf(alpha * acc3 + beta * bf2f(pv[3]));
        } else {
            r[0] = f2bf(alpha * acc0); r[1] = f2bf(alpha * acc1);
            r[2] = f2bf(alpha * acc2); r[3] = f2bf(alpha * acc3);
        }
        *(u16x4*)op = r;
    }
}

// ---------------------------------------------------------------------------
// GRU elementwise tail (bf16 gi/gh/hid, f32 out), 8 cols/thread.
// ---------------------------------------------------------------------------
__global__ __launch_bounds__(256) void gru_elem(
    const unsigned short* __restrict__ gi, const unsigned short* __restrict__ gh,
    const unsigned short* __restrict__ hid, float* __restrict__ out) {
    int idx = blockIdx.x * 256 + threadIdx.x;   // over rows*96
    int nrow = idx / 96, c8 = (idx % 96) * 8;
    const unsigned short* gip = gi + (size_t)nrow * 2304 + c8;
    const unsigned short* ghp = gh + (size_t)nrow * 2304 + c8;
    u16x8 vir = *(const u16x8*)(gip);
    u16x8 viz = *(const u16x8*)(gip + 768);
    u16x8 vin = *(const u16x8*)(gip + 1536);
    u16x8 vhr = *(const u16x8*)(ghp);
    u16x8 vhz = *(const u16x8*)(ghp + 768);
    u16x8 vhn = *(const u16x8*)(ghp + 1536);
    u16x8 vh  = *(const u16x8*)(hid + (size_t)nrow * 768 + c8);
    float res[8];
    #pragma unroll
    for (int e = 0; e < 8; e++) {
        float r = 1.f / (1.f + expf(-(bf2f(vir[e]) + bf2f(vhr[e]))));
        float z = 1.f / (1.f + expf(-(bf2f(viz[e]) + bf2f(vhz[e]))));
        float cand = tanhf(bf2f(vin[e]) + r * bf2f(vhn[e]));
        res[e] = (1.f - z) * cand + z * bf2f(vh[e]);
    }
    float* op = out + (size_t)nrow * 768 + c8;
    *(float4*)(op)     = make_float4(res[0], res[1], res[2], res[3]);
    *(float4*)(op + 4) = make_float4(res[4], res[5], res[6], res[7]);
}

// ---------------------------------------------------------------------------
// Launch. ws (bf16 elems): Xb[SZ] | Hdb[SZ] | GIb[CH*2304] | GHb[CH*2304] |
//   W2gT W2xT WihB WhhB | f32 ES ED ESI EDI.
// AB (transient bf16 [NT,768] input-conversion buffer) aliases GIb/GHb
// (dead until GRU phase). P (bf16 [NT,768] proj scratch) lives in d_out.
// Total ws ~190 MB (same as round 5).
// ---------------------------------------------------------------------------
extern "C" void kernel_launch(void* const* d_in, const int* in_sizes, int n_in,
                              void* d_out, int out_size, void* d_ws, size_t ws_size,
                              hipStream_t stream) {
    const float* h    = (const float*)d_in[0];
    const float* hbc  = (const float*)d_in[1];
    const float* hbs  = (const float*)d_in[2];
    const float* Wg   = (const float*)d_in[3];
    const float* bg   = (const float*)d_in[4];
    const float* ag   = (const float*)d_in[5];
    const float* agb  = (const float*)d_in[6];
    const float* Wx   = (const float*)d_in[7];
    const float* bx   = (const float*)d_in[8];
    const float* ax   = (const float*)d_in[9];
    const float* axb  = (const float*)d_in[10];
    const float* Wih  = (const float*)d_in[11];
    const float* Whh  = (const float*)d_in[12];
    const float* bih  = (const float*)d_in[13];
    const float* bhh  = (const float*)d_in[14];
    const int* i_src  = (const int*)d_in[15];
    const int* i_dst  = (const int*)d_in[16];
    const int* c_src  = (const int*)d_in[17];
    const int* c_dst  = (const int*)d_in[18];
    const int* s_src  = (const int*)d_in[19];
    const int* s_dst  = (const int*)d_in[20];
    float* out = (float*)d_out;

    const size_t SZ = (size_t)NT * 768;
    unsigned short* Xb  = (unsigned short*)d_ws;
    unsigned short* Hdb = Xb + SZ;
    unsigned short* GIb = Hdb + SZ;
    unsigned short* GHb = GIb + (size_t)CH * 2304;
    unsigned short* AB  = GIb;                      // transient cvt buffer (aliases GI/GH)
    unsigned short* W2gT = GHb + (size_t)CH * 2304;
    unsigned short* W2xT = W2gT + 768 * 768;
    unsigned short* WihB = W2xT + 768 * 768;
    unsigned short* WhhB = WihB + 2304 * 768;
    float* ES  = (float*)(WhhB + 2304 * 768);
    float* ED  = ES + NE;
    float* ESI = ED + NE;
    float* EDI = ESI + NE;
    unsigned short* Pb = (unsigned short*)d_out;    // bf16 scratch in d_out

    dim3 blk(256);
    packWT<<<(768 * 768 + 255) / 256, blk, 0, stream>>>(Wg, W2gT);
    packWT<<<(768 * 768 + 255) / 256, blk, 0, stream>>>(Wx, W2xT);
    cvt_bf8<<<(2304 * 768 / 8 + 255) / 256, blk, 0, stream>>>(Wih, WihB, 2304 * 768 / 8);
    cvt_bf8<<<(2304 * 768 / 8 + 255) / 256, blk, 0, stream>>>(Whh, WhhB, 2304 * 768 / 8);

    dim3 g768(6, NT / 128);      // (6, 256)
    const int n8 = (int)(SZ / 8);
    const int cvtg = (n8 + 255) / 256;

    // 1) Wh = h @ Wg + bg -> Pb
    cvt_bf8<<<cvtg, blk, 0, stream>>>(h, AB, n8);
    mgemm_bb<<<g768, blk, 0, stream>>>(AB, W2gT, bg, Pb, NT, 768, 768);
    // 2) intra scores + attend -> Xb
    escore<<<NE / 256, blk, 0, stream>>>(Pb, ag, 0, ESI);
    escore<<<NE / 256, blk, 0, stream>>>(Pb, ag, 1, EDI);
    attend_agg<<<NT / 4, blk, 0, stream>>>(Pb, ESI, EDI, agb, i_src, i_dst, Xb, 1.f, 0.f);
    // 3) Wx_d = X @ Wx + bx -> Pb ; dst scores
    mgemm_bb<<<g768, blk, 0, stream>>>(Xb, W2xT, bx, Pb, NT, 768, 768);
    escore<<<NE / 256, blk, 0, stream>>>(Pb, ax, 1, ED);
    // 4) counter branch
    cvt_bf8<<<cvtg, blk, 0, stream>>>(hbc, AB, n8);
    mgemm_bb<<<g768, blk, 0, stream>>>(AB, W2xT, bx, Pb, NT, 768, 768);
    escore<<<NE / 256, blk, 0, stream>>>(Pb, ax, 0, ES);
    attend_agg<<<NT / 4, blk, 0, stream>>>(Pb, ES, ED, axb, c_src, c_dst, Hdb, 0.5f, 0.f);
    // 5) support branch
    cvt_bf8<<<cvtg, blk, 0, stream>>>(hbs, AB, n8);
    mgemm_bb<<<g768, blk, 0, stream>>>(AB, W2xT, bx, Pb, NT, 768, 768);
    escore<<<NE / 256, blk, 0, stream>>>(Pb, ax, 0, ES);
    attend_agg<<<NT / 4, blk, 0, stream>>>(Pb, ES, ED, axb, s_src, s_dst, Hdb, 0.5f, 1.f);

    // 6) GRU, row-chunked  (AB dead from here; GIb/GHb live)
    dim3 gch(2304 / 128, CH / 128);   // (18, 64)
    for (int c0 = 0; c0 < NT; c0 += CH) {
        mgemm_bb<<<gch, blk, 0, stream>>>(Xb  + (size_t)c0 * 768, WihB, bih, GIb, CH, 2304, 768);
        mgemm_bb<<<gch, blk, 0, stream>>>(Hdb + (size_t)c0 * 768, WhhB, bhh, GHb, CH, 2304, 768);
        gru_elem<<<(CH * 96) / 256, blk, 0, stream>>>(GIb, GHb, Hdb + (size_t)c0 * 768, out + (size_t)c0 * 768);
    }
}

// Round 7
// 1009.845 us; speedup vs baseline: 23.1696x; 1.0206x over previous
//
#include <hip/hip_runtime.h>
#include <hip/hip_bf16.h>
#include <math.h>

// Problem constants
#define NT 32768
#define HD 96
#define DEG 8
#define NE (NT * DEG)
#define LRELU_ALPHA 0.2f
#define CH 8192              // GRU row-chunk

typedef __attribute__((ext_vector_type(8))) short bf16x8;     // 8 bf16 (4 VGPRs)
typedef __attribute__((ext_vector_type(8))) unsigned short u16x8;
typedef __attribute__((ext_vector_type(4))) unsigned short u16x4;
typedef __attribute__((ext_vector_type(4))) float f32x4;

__device__ __forceinline__ unsigned short f2bf(float x) {
    union { float f; unsigned u; } v; v.f = x;
    unsigned r = v.u + 0x7FFFu + ((v.u >> 16) & 1u);   // RNE
    return (unsigned short)(r >> 16);
}
__device__ __forceinline__ float bf2f(unsigned short u) {
    union { unsigned u; float f; } v; v.u = ((unsigned)u) << 16; return v.f;
}

__device__ __forceinline__ void gload_lds16(const void* g, void* l) {
    __builtin_amdgcn_global_load_lds(
        (const __attribute__((address_space(1))) void*)g,
        (__attribute__((address_space(3))) void*)l, 16, 0, 0);
}

// ---------------------------------------------------------------------------
// Pack kernels
// ---------------------------------------------------------------------------

// W [H,768,96] f32 -> T bf16 [768 c][768 f], T[c][f] = W[c/96][f][c%96]
__global__ void packWT(const float* __restrict__ W, unsigned short* __restrict__ T) {
    int idx = blockIdx.x * 256 + threadIdx.x;
    if (idx >= 768 * 768) return;
    int c = idx / 768, f = idx % 768;
    T[idx] = f2bf(W[(size_t)(c / HD) * 768 * HD + (size_t)f * HD + (c % HD)]);
}

// vectorized f32 -> bf16 (8 elems/thread); n8 = n/8
__global__ void cvt_bf8(const float* __restrict__ X, unsigned short* __restrict__ Y, int n8) {
    int i = blockIdx.x * 256 + threadIdx.x;
    if (i >= n8) return;
    float4 a = ((const float4*)X)[2 * i];
    float4 b = ((const float4*)X)[2 * i + 1];
    u16x8 p;
    p[0] = f2bf(a.x); p[1] = f2bf(a.y); p[2] = f2bf(a.z); p[3] = f2bf(a.w);
    p[4] = f2bf(b.x); p[5] = f2bf(b.y); p[6] = f2bf(b.z); p[7] = f2bf(b.w);
    ((u16x8*)Y)[i] = p;
}

// ---------------------------------------------------------------------------
// MFMA GEMM, bf16 A and BT, double-buffered LDS (one barrier per K-step:
// prefetch tile t+1 into buf^1 right after the barrier, compute tile t; the
// next loop-top __syncthreads drains the prefetch after a full compute phase).
// XOR source-preswizzle (slot s holds k-word s^((row>>1)&3)); XCD swizzle.
// 128x128 tile, BK=32, 256 thr (4 waves 2x2), 4 blocks/CU.
// ---------------------------------------------------------------------------
__global__ __launch_bounds__(256, 4) void mgemm_bb(
    const unsigned short* __restrict__ A, const unsigned short* __restrict__ BT,
    const float* __restrict__ bias, unsigned short* __restrict__ C,
    int M, int N, int K) {
    __shared__ unsigned short Alds[2][128 * 32];
    __shared__ unsigned short Blds[2][128 * 32];
    const int tid = threadIdx.x;
    const int w = tid >> 6, l = tid & 63;
    const int wr = w >> 1, wc = w & 1;
    const int lrow = l & 15, lk = l >> 4;

    // XCD-aware swizzle: consecutive tiles on one XCD share an A panel.
    const int nx = gridDim.x;
    const int nwg = nx * gridDim.y;
    int lin = blockIdx.y * nx + blockIdx.x;
    if ((nwg & 7) == 0) lin = (lin & 7) * (nwg >> 3) + (lin >> 3);
    const int bm = lin / nx, bn = lin % nx;

    const unsigned short* asrc[2];
    const unsigned short* bsrc[2];
    #pragma unroll
    for (int q = 0; q < 2; q++) {
        int idx = q * 256 + tid;
        int r = idx >> 2, s = idx & 3;
        int kw = s ^ ((r >> 1) & 3);
        asrc[q] = A  + (size_t)(bm * 128 + r) * K + kw * 8;
        bsrc[q] = BT + (size_t)(bn * 128 + r) * K + kw * 8;
    }
    const int ldst = (w * 64) * 8;   // wave-uniform LDS slot base (q adds 256*8)

    // prologue: stage tile 0 into buffer 0
    gload_lds16(asrc[0], &Alds[0][ldst]);
    gload_lds16(asrc[1], &Alds[0][2048 + ldst]);
    gload_lds16(bsrc[0], &Blds[0][ldst]);
    gload_lds16(bsrc[1], &Blds[0][2048 + ldst]);

    f32x4 acc[4][4] = {};
    const int nt = K >> 5;

    for (int t = 0; t < nt; ++t) {
        const int cur = t & 1;
        __syncthreads();                       // drains prior tile's loads
        if (t + 1 < nt) {                      // prefetch next tile (overlaps MFMA)
            const int k1 = (t + 1) << 5;
            gload_lds16(asrc[0] + k1, &Alds[cur ^ 1][ldst]);
            gload_lds16(asrc[1] + k1, &Alds[cur ^ 1][2048 + ldst]);
            gload_lds16(bsrc[0] + k1, &Blds[cur ^ 1][ldst]);
            gload_lds16(bsrc[1] + k1, &Blds[cur ^ 1][2048 + ldst]);
        }
        bf16x8 af[4], bfv[4];
        #pragma unroll
        for (int i = 0; i < 4; i++) {
            int r = wr * 64 + i * 16 + lrow;
            int s = lk ^ ((r >> 1) & 3);
            af[i] = *(const bf16x8*)(&Alds[cur][r * 32 + s * 8]);
        }
        #pragma unroll
        for (int j = 0; j < 4; j++) {
            int r = wc * 64 + j * 16 + lrow;
            int s = lk ^ ((r >> 1) & 3);
            bfv[j] = *(const bf16x8*)(&Blds[cur][r * 32 + s * 8]);
        }
        #pragma unroll
        for (int i = 0; i < 4; i++)
            #pragma unroll
            for (int j = 0; j < 4; j++)
                acc[i][j] = __builtin_amdgcn_mfma_f32_16x16x32_bf16(af[i], bfv[j], acc[i][j], 0, 0, 0);
    }

    const size_t crow0 = (size_t)bm * 128 + wr * 64;
    const int ccol0 = bn * 128 + wc * 64;
    #pragma unroll
    for (int j = 0; j < 4; j++) {
        int col = ccol0 + j * 16 + lrow;
        float bv = bias[col];
        #pragma unroll
        for (int i = 0; i < 4; i++) {
            size_t row = crow0 + i * 16 + lk * 4;
            #pragma unroll
            for (int e = 0; e < 4; e++)
                C[(row + e) * N + col] = f2bf(acc[i][j][e] + bv);
        }
    }
}

// ---------------------------------------------------------------------------
// Fused dual edge score (src & dst halves in one pass over X):
//   s0[n*8+h] = sum_d X[n][h*96+d]*a[h][d],  s1[...] = sum_d X*a[h][96+d]
// ---------------------------------------------------------------------------
__global__ __launch_bounds__(256) void escore2(
    const unsigned short* __restrict__ X, const float* __restrict__ a,
    float* __restrict__ s0out, float* __restrict__ s1out) {
    __shared__ float av0[768], av1[768];
    for (int t = threadIdx.x; t < 768; t += 256) {
        int hh = t / HD, d = t % HD;
        av0[t] = a[hh * 2 * HD + d];
        av1[t] = a[hh * 2 * HD + HD + d];
    }
    __syncthreads();
    int idx = blockIdx.x * 256 + threadIdx.x;   // (n,h)
    int row = idx >> 3, hh = idx & 7;
    const unsigned short* xp = X + (size_t)row * 768 + hh * HD;
    const float* a0 = av0 + hh * HD;
    const float* a1 = av1 + hh * HD;
    float s0 = 0.f, s1 = 0.f;
    #pragma unroll
    for (int q = 0; q < 12; q++) {
        u16x8 v = *(const u16x8*)(xp + q * 8);
        #pragma unroll
        for (int e = 0; e < 8; e++) {
            float x = bf2f(v[e]);
            s0 += x * a0[q * 8 + e];
            s1 += x * a1[q * 8 + e];
        }
    }
    s0out[idx] = s0;
    s1out[idx] = s1;
}

// single-half edge score (for ED / per-branch src scores)
__global__ __launch_bounds__(256) void escore(
    const unsigned short* __restrict__ X, const float* __restrict__ a,
    int half, float* __restrict__ sc) {
    __shared__ float av[768];
    for (int t = threadIdx.x; t < 768; t += 256) {
        int hh = t / HD, d = t % HD;
        av[t] = a[hh * 2 * HD + half * HD + d];
    }
    __syncthreads();
    int idx = blockIdx.x * 256 + threadIdx.x;
    int row = idx >> 3, hh = idx & 7;
    const unsigned short* xp = X + (size_t)row * 768 + hh * HD;
    const float* ap = av + hh * HD;
    float s = 0.f;
    #pragma unroll
    for (int q = 0; q < 12; q++) {
        u16x8 v = *(const u16x8*)(xp + q * 8);
        #pragma unroll
        for (int e = 0; e < 8; e++) s += bf2f(v[e]) * ap[q * 8 + e];
    }
    sc[idx] = s;
}

// ---------------------------------------------------------------------------
// Per-dst softmax + aggregate, one WAVE per dst segment. (intra branch)
// ---------------------------------------------------------------------------
__global__ __launch_bounds__(256) void attend_agg(
    const unsigned short* __restrict__ Whs, const float* __restrict__ es,
    const float* __restrict__ ed, const float* __restrict__ ab,
    const int* __restrict__ src, const int* __restrict__ dst,
    unsigned short* __restrict__ out) {
    const int wv = threadIdx.x >> 6, l = threadIdx.x & 63;
    const int seg = blockIdx.x * 4 + wv;
    const int hh = l >> 3, j = l & 7;
    int sj = src[seg * 8 + j];
    int dnode = dst[seg * 8];
    float e = es[(size_t)sj * 8 + hh] + ed[(size_t)dnode * 8 + hh] + ab[hh];
    e = e > 0.f ? e : LRELU_ALPHA * e;
    float m = e;
    #pragma unroll
    for (int o = 1; o < 8; o <<= 1) m = fmaxf(m, __shfl_xor(m, o, 64));
    float ex = expf(e - m);
    float s = ex;
    #pragma unroll
    for (int o = 1; o < 8; o <<= 1) s += __shfl_xor(s, o, 64);
    float att = ex / s;

    #pragma unroll
    for (int u = 0; u < 3; u++) {
        int c = 4 * l + 256 * u;
        int h = c / HD;
        float acc0 = 0.f, acc1 = 0.f, acc2 = 0.f, acc3 = 0.f;
        #pragma unroll
        for (int j2 = 0; j2 < 8; j2++) {
            float a = __shfl(att, h * 8 + j2, 64);
            int sid = __shfl(sj, j2, 64);
            u16x4 v = *(const u16x4*)(Whs + (size_t)sid * 768 + c);
            acc0 += a * bf2f(v[0]); acc1 += a * bf2f(v[1]);
            acc2 += a * bf2f(v[2]); acc3 += a * bf2f(v[3]);
        }
        u16x4 r;
        r[0] = f2bf(acc0); r[1] = f2bf(acc1); r[2] = f2bf(acc2); r[3] = f2bf(acc3);
        *(u16x4*)(out + (size_t)dnode * 768 + c) = r;
    }
}

// ---------------------------------------------------------------------------
// Fused counter+support attend: Hd = 0.5*attend(Wc, esC) + 0.5*attend(Ws, esS).
// Both mailboxes share dst. Writes Hd exactly once.
// ---------------------------------------------------------------------------
__global__ __launch_bounds__(256) void attend2(
    const unsigned short* __restrict__ Wc, const unsigned short* __restrict__ Ws,
    const float* __restrict__ esC, const float* __restrict__ esS,
    const float* __restrict__ ed, const float* __restrict__ ab,
    const int* __restrict__ csrc, const int* __restrict__ ssrc,
    const int* __restrict__ dst, unsigned short* __restrict__ outH) {
    const int wv = threadIdx.x >> 6, l = threadIdx.x & 63;
    const int seg = blockIdx.x * 4 + wv;
    const int hh = l >> 3, j = l & 7;
    int cj = csrc[seg * 8 + j];
    int sj = ssrc[seg * 8 + j];
    int dnode = dst[seg * 8];
    float edv = ed[(size_t)dnode * 8 + hh] + ab[hh];

    float eC = esC[(size_t)cj * 8 + hh] + edv;
    eC = eC > 0.f ? eC : LRELU_ALPHA * eC;
    float mC = eC;
    #pragma unroll
    for (int o = 1; o < 8; o <<= 1) mC = fmaxf(mC, __shfl_xor(mC, o, 64));
    float exC = expf(eC - mC);
    float sC = exC;
    #pragma unroll
    for (int o = 1; o < 8; o <<= 1) sC += __shfl_xor(sC, o, 64);
    float attC = exC / sC;

    float eS = esS[(size_t)sj * 8 + hh] + edv;
    eS = eS > 0.f ? eS : LRELU_ALPHA * eS;
    float mS = eS;
    #pragma unroll
    for (int o = 1; o < 8; o <<= 1) mS = fmaxf(mS, __shfl_xor(mS, o, 64));
    float exS = expf(eS - mS);
    float sS = exS;
    #pragma unroll
    for (int o = 1; o < 8; o <<= 1) sS += __shfl_xor(sS, o, 64);
    float attS = exS / sS;

    #pragma unroll
    for (int u = 0; u < 3; u++) {
        int c = 4 * l + 256 * u;
        int h = c / HD;
        float acc0 = 0.f, acc1 = 0.f, acc2 = 0.f, acc3 = 0.f;
        #pragma unroll
        for (int j2 = 0; j2 < 8; j2++) {
            float a = __shfl(attC, h * 8 + j2, 64);
            int sid = __shfl(cj, j2, 64);
            u16x4 v = *(const u16x4*)(Wc + (size_t)sid * 768 + c);
            acc0 += a * bf2f(v[0]); acc1 += a * bf2f(v[1]);
            acc2 += a * bf2f(v[2]); acc3 += a * bf2f(v[3]);
        }
        #pragma unroll
        for (int j2 = 0; j2 < 8; j2++) {
            float a = __shfl(attS, h * 8 + j2, 64);
            int sid = __shfl(sj, j2, 64);
            u16x4 v = *(const u16x4*)(Ws + (size_t)sid * 768 + c);
            acc0 += a * bf2f(v[0]); acc1 += a * bf2f(v[1]);
            acc2 += a * bf2f(v[2]); acc3 += a * bf2f(v[3]);
        }
        u16x4 r;
        r[0] = f2bf(0.5f * acc0); r[1] = f2bf(0.5f * acc1);
        r[2] = f2bf(0.5f * acc2); r[3] = f2bf(0.5f * acc3);
        *(u16x4*)(outH + (size_t)dnode * 768 + c) = r;
    }
}

// ---------------------------------------------------------------------------
// GRU elementwise tail (bf16 gi/gh/hid, f32 out), 8 cols/thread.
// ---------------------------------------------------------------------------
__global__ __launch_bounds__(256) void gru_elem(
    const unsigned short* __restrict__ gi, const unsigned short* __restrict__ gh,
    const unsigned short* __restrict__ hid, float* __restrict__ out) {
    int idx = blockIdx.x * 256 + threadIdx.x;   // over rows*96
    int nrow = idx / 96, c8 = (idx % 96) * 8;
    const unsigned short* gip = gi + (size_t)nrow * 2304 + c8;
    const unsigned short* ghp = gh + (size_t)nrow * 2304 + c8;
    u16x8 vir = *(const u16x8*)(gip);
    u16x8 viz = *(const u16x8*)(gip + 768);
    u16x8 vin = *(const u16x8*)(gip + 1536);
    u16x8 vhr = *(const u16x8*)(ghp);
    u16x8 vhz = *(const u16x8*)(ghp + 768);
    u16x8 vhn = *(const u16x8*)(ghp + 1536);
    u16x8 vh  = *(const u16x8*)(hid + (size_t)nrow * 768 + c8);
    float res[8];
    #pragma unroll
    for (int e = 0; e < 8; e++) {
        float r = 1.f / (1.f + expf(-(bf2f(vir[e]) + bf2f(vhr[e]))));
        float z = 1.f / (1.f + expf(-(bf2f(viz[e]) + bf2f(vhz[e]))));
        float cand = tanhf(bf2f(vin[e]) + r * bf2f(vhn[e]));
        res[e] = (1.f - z) * cand + z * bf2f(vh[e]);
    }
    float* op = out + (size_t)nrow * 768 + c8;
    *(float4*)(op)     = make_float4(res[0], res[1], res[2], res[3]);
    *(float4*)(op + 4) = make_float4(res[4], res[5], res[6], res[7]);
}

// ---------------------------------------------------------------------------
// Launch. ws (bf16 elems): Xb[SZ] | Hdb[SZ] | GIb[CH*2304] | GHb[CH*2304] |
//   W2gT W2xT WihB WhhB | f32 ES ED ESI EDI | P2b[SZ].
// AB (transient cvt buffer) aliases GIb (dead until GRU). Pb = d_out.
// Total ws ~240 MB (proven ceiling 291 MB).
// ---------------------------------------------------------------------------
extern "C" void kernel_launch(void* const* d_in, const int* in_sizes, int n_in,
                              void* d_out, int out_size, void* d_ws, size_t ws_size,
                              hipStream_t stream) {
    const float* h    = (const float*)d_in[0];
    const float* hbc  = (const float*)d_in[1];
    const float* hbs  = (const float*)d_in[2];
    const float* Wg   = (const float*)d_in[3];
    const float* bg   = (const float*)d_in[4];
    const float* ag   = (const float*)d_in[5];
    const float* agb  = (const float*)d_in[6];
    const float* Wx   = (const float*)d_in[7];
    const float* bx   = (const float*)d_in[8];
    const float* ax   = (const float*)d_in[9];
    const float* axb  = (const float*)d_in[10];
    const float* Wih  = (const float*)d_in[11];
    const float* Whh  = (const float*)d_in[12];
    const float* bih  = (const float*)d_in[13];
    const float* bhh  = (const float*)d_in[14];
    const int* i_src  = (const int*)d_in[15];
    const int* i_dst  = (const int*)d_in[16];
    const int* c_src  = (const int*)d_in[17];
    const int* c_dst  = (const int*)d_in[18];
    const int* s_src  = (const int*)d_in[19];
    const int* s_dst  = (const int*)d_in[20];
    float* out = (float*)d_out;

    const size_t SZ = (size_t)NT * 768;
    unsigned short* Xb  = (unsigned short*)d_ws;
    unsigned short* Hdb = Xb + SZ;
    unsigned short* GIb = Hdb + SZ;
    unsigned short* GHb = GIb + (size_t)CH * 2304;
    unsigned short* AB  = GIb;                      // transient cvt buffer
    unsigned short* W2gT = GHb + (size_t)CH * 2304;
    unsigned short* W2xT = W2gT + 768 * 768;
    unsigned short* WihB = W2xT + 768 * 768;
    unsigned short* WhhB = WihB + 2304 * 768;
    float* ES  = (float*)(WhhB + 2304 * 768);
    float* ED  = ES + NE;
    float* ESI = ED + NE;
    float* EDI = ESI + NE;
    unsigned short* P2b = (unsigned short*)(EDI + NE);   // second projection
    unsigned short* Pb = (unsigned short*)d_out;         // bf16 scratch in d_out

    dim3 blk(256);
    packWT<<<(768 * 768 + 255) / 256, blk, 0, stream>>>(Wg, W2gT);
    packWT<<<(768 * 768 + 255) / 256, blk, 0, stream>>>(Wx, W2xT);
    cvt_bf8<<<(2304 * 768 / 8 + 255) / 256, blk, 0, stream>>>(Wih, WihB, 2304 * 768 / 8);
    cvt_bf8<<<(2304 * 768 / 8 + 255) / 256, blk, 0, stream>>>(Whh, WhhB, 2304 * 768 / 8);

    dim3 g768(6, NT / 128);      // (6, 256)
    const int n8 = (int)(SZ / 8);
    const int cvtg = (n8 + 255) / 256;

    // 1) Wh = h @ Wg + bg -> Pb
    cvt_bf8<<<cvtg, blk, 0, stream>>>(h, AB, n8);
    mgemm_bb<<<g768, blk, 0, stream>>>(AB, W2gT, bg, Pb, NT, 768, 768);
    // 2) intra: both score halves in one pass, attend -> Xb
    escore2<<<NE / 256, blk, 0, stream>>>(Pb, ag, ESI, EDI);
    attend_agg<<<NT / 4, blk, 0, stream>>>(Pb, ESI, EDI, agb, i_src, i_dst, Xb);
    // 3) Wx_d = X @ Wx + bx -> Pb ; dst scores
    mgemm_bb<<<g768, blk, 0, stream>>>(Xb, W2xT, bx, Pb, NT, 768, 768);
    escore<<<NE / 256, blk, 0, stream>>>(Pb, ax, 1, ED);
    // 4) counter projection -> Pb is needed for attend; use P2b for support.
    //    (Pb currently holds Wx_d; ED already extracted, safe to overwrite.)
    cvt_bf8<<<cvtg, blk, 0, stream>>>(hbc, AB, n8);
    mgemm_bb<<<g768, blk, 0, stream>>>(AB, W2xT, bx, Pb, NT, 768, 768);
    escore<<<NE / 256, blk, 0, stream>>>(Pb, ax, 0, ES);
    // 5) support projection -> P2b
    cvt_bf8<<<cvtg, blk, 0, stream>>>(hbs, AB, n8);
    mgemm_bb<<<g768, blk, 0, stream>>>(AB, W2xT, bx, P2b, NT, 768, 768);
    escore<<<NE / 256, blk, 0, stream>>>(P2b, ax, 0, ESI);   // ESI reused as ES_support
    // fused counter+support attend -> Hdb (written once)
    attend2<<<NT / 4, blk, 0, stream>>>(Pb, P2b, ES, ESI, ED, axb, c_src, s_src, c_dst, Hdb);

    // 6) GRU, row-chunked  (AB dead from here; GIb/GHb live)
    dim3 gch(2304 / 128, CH / 128);   // (18, 64)
    for (int c0 = 0; c0 < NT; c0 += CH) {
        mgemm_bb<<<gch, blk, 0, stream>>>(Xb  + (size_t)c0 * 768, WihB, bih, GIb, CH, 2304, 768);
        mgemm_bb<<<gch, blk, 0, stream>>>(Hdb + (size_t)c0 * 768, WhhB, bhh, GHb, CH, 2304, 768);
        gru_elem<<<(CH * 96) / 256, blk, 0, stream>>>(GIb, GHb, Hdb + (size_t)c0 * 768, out + (size_t)c0 * 768);
    }
}

// Round 8
// 927.139 us; speedup vs baseline: 25.2365x; 1.0892x over previous
//
#include <hip/hip_runtime.h>
#include <hip/hip_bf16.h>
#include <math.h>

// Problem constants
#define NT 32768
#define HD 96
#define DEG 8
#define NE (NT * DEG)
#define LRELU_ALPHA 0.2f
#define CH 16384             // GRU row-chunk

typedef __attribute__((ext_vector_type(8))) short bf16x8;     // 8 bf16 (4 VGPRs)
typedef __attribute__((ext_vector_type(8))) unsigned short u16x8;
typedef __attribute__((ext_vector_type(4))) unsigned short u16x4;
typedef __attribute__((ext_vector_type(4))) float f32x4;

__device__ __forceinline__ unsigned short f2bf(float x) {
    union { float f; unsigned u; } v; v.f = x;
    unsigned r = v.u + 0x7FFFu + ((v.u >> 16) & 1u);   // RNE
    return (unsigned short)(r >> 16);
}
__device__ __forceinline__ float bf2f(unsigned short u) {
    union { unsigned u; float f; } v; v.u = ((unsigned)u) << 16; return v.f;
}

__device__ __forceinline__ void gload_lds16(const void* g, void* l) {
    __builtin_amdgcn_global_load_lds(
        (const __attribute__((address_space(1))) void*)g,
        (__attribute__((address_space(3))) void*)l, 16, 0, 0);
}

// ---------------------------------------------------------------------------
// Pack kernels
// ---------------------------------------------------------------------------

// W [H,768,96] f32 -> T bf16 [768 c][768 f], T[c][f] = W[c/96][f][c%96]
__global__ void packWT(const float* __restrict__ W, unsigned short* __restrict__ T) {
    int idx = blockIdx.x * 256 + threadIdx.x;
    if (idx >= 768 * 768) return;
    int c = idx / 768, f = idx % 768;
    T[idx] = f2bf(W[(size_t)(c / HD) * 768 * HD + (size_t)f * HD + (c % HD)]);
}

// vectorized f32 -> bf16 (8 elems/thread); n8 = n/8
__global__ void cvt_bf8(const float* __restrict__ X, unsigned short* __restrict__ Y, int n8) {
    int i = blockIdx.x * 256 + threadIdx.x;
    if (i >= n8) return;
    float4 a = ((const float4*)X)[2 * i];
    float4 b = ((const float4*)X)[2 * i + 1];
    u16x8 p;
    p[0] = f2bf(a.x); p[1] = f2bf(a.y); p[2] = f2bf(a.z); p[3] = f2bf(a.w);
    p[4] = f2bf(b.x); p[5] = f2bf(b.y); p[6] = f2bf(b.z); p[7] = f2bf(b.w);
    ((u16x8*)Y)[i] = p;
}

// Fold Wx against ax_dst: wv[h*768+f] = sum_d Wx[h][f][d]*ax[h][96+d];
// cd[h] = sum_d bx[h][d]*ax[h][96+d]
__global__ void packWV(const float* __restrict__ Wx, const float* __restrict__ ax,
                       const float* __restrict__ bx,
                       float* __restrict__ wv, float* __restrict__ cd) {
    int idx = blockIdx.x * 256 + threadIdx.x;
    if (idx < 8 * 768) {
        int h = idx / 768, f = idx % 768;
        const float* wp = Wx + (size_t)h * 768 * HD + (size_t)f * HD;
        const float* ap = ax + h * 2 * HD + HD;
        float s = 0.f;
        for (int d = 0; d < HD; d++) s += wp[d] * ap[d];
        wv[idx] = s;
    }
    if (idx < 8) {
        const float* bp = bx + idx * HD;
        const float* ap = ax + idx * 2 * HD + HD;
        float s = 0.f;
        for (int d = 0; d < HD; d++) s += bp[d] * ap[d];
        cd[idx] = s;
    }
}

// ---------------------------------------------------------------------------
// MFMA GEMM, bf16 A and BT, double-buffered LDS, XOR source-preswizzle
// (slot s holds k-word s^((row>>1)&3)), XCD-aware tile swizzle.
// 128x128 tile, BK=32, 256 thr (4 waves 2x2). (round-7 proven)
// ---------------------------------------------------------------------------
__global__ __launch_bounds__(256, 4) void mgemm_bb(
    const unsigned short* __restrict__ A, const unsigned short* __restrict__ BT,
    const float* __restrict__ bias, unsigned short* __restrict__ C,
    int M, int N, int K) {
    __shared__ unsigned short Alds[2][128 * 32];
    __shared__ unsigned short Blds[2][128 * 32];
    const int tid = threadIdx.x;
    const int w = tid >> 6, l = tid & 63;
    const int wr = w >> 1, wc = w & 1;
    const int lrow = l & 15, lk = l >> 4;

    const int nx = gridDim.x;
    const int nwg = nx * gridDim.y;
    int lin = blockIdx.y * nx + blockIdx.x;
    if ((nwg & 7) == 0) lin = (lin & 7) * (nwg >> 3) + (lin >> 3);
    const int bm = lin / nx, bn = lin % nx;

    const unsigned short* asrc[2];
    const unsigned short* bsrc[2];
    #pragma unroll
    for (int q = 0; q < 2; q++) {
        int idx = q * 256 + tid;
        int r = idx >> 2, s = idx & 3;
        int kw = s ^ ((r >> 1) & 3);
        asrc[q] = A  + (size_t)(bm * 128 + r) * K + kw * 8;
        bsrc[q] = BT + (size_t)(bn * 128 + r) * K + kw * 8;
    }
    const int ldst = (w * 64) * 8;

    gload_lds16(asrc[0], &Alds[0][ldst]);
    gload_lds16(asrc[1], &Alds[0][2048 + ldst]);
    gload_lds16(bsrc[0], &Blds[0][ldst]);
    gload_lds16(bsrc[1], &Blds[0][2048 + ldst]);

    f32x4 acc[4][4] = {};
    const int nt = K >> 5;

    for (int t = 0; t < nt; ++t) {
        const int cur = t & 1;
        __syncthreads();
        if (t + 1 < nt) {
            const int k1 = (t + 1) << 5;
            gload_lds16(asrc[0] + k1, &Alds[cur ^ 1][ldst]);
            gload_lds16(asrc[1] + k1, &Alds[cur ^ 1][2048 + ldst]);
            gload_lds16(bsrc[0] + k1, &Blds[cur ^ 1][ldst]);
            gload_lds16(bsrc[1] + k1, &Blds[cur ^ 1][2048 + ldst]);
        }
        bf16x8 af[4], bfv[4];
        #pragma unroll
        for (int i = 0; i < 4; i++) {
            int r = wr * 64 + i * 16 + lrow;
            int s = lk ^ ((r >> 1) & 3);
            af[i] = *(const bf16x8*)(&Alds[cur][r * 32 + s * 8]);
        }
        #pragma unroll
        for (int j = 0; j < 4; j++) {
            int r = wc * 64 + j * 16 + lrow;
            int s = lk ^ ((r >> 1) & 3);
            bfv[j] = *(const bf16x8*)(&Blds[cur][r * 32 + s * 8]);
        }
        #pragma unroll
        for (int i = 0; i < 4; i++)
            #pragma unroll
            for (int j = 0; j < 4; j++)
                acc[i][j] = __builtin_amdgcn_mfma_f32_16x16x32_bf16(af[i], bfv[j], acc[i][j], 0, 0, 0);
    }

    const size_t crow0 = (size_t)bm * 128 + wr * 64;
    const int ccol0 = bn * 128 + wc * 64;
    #pragma unroll
    for (int j = 0; j < 4; j++) {
        int col = ccol0 + j * 16 + lrow;
        float bv = bias[col];
        #pragma unroll
        for (int i = 0; i < 4; i++) {
            size_t row = crow0 + i * 16 + lk * 4;
            #pragma unroll
            for (int e = 0; e < 4; e++)
                C[(row + e) * N + col] = f2bf(acc[i][j][e] + bv);
        }
    }
}

// ---------------------------------------------------------------------------
// Fused dual edge score (intra): both halves in one pass over X.
// ---------------------------------------------------------------------------
__global__ __launch_bounds__(256) void escore2(
    const unsigned short* __restrict__ X, const float* __restrict__ a,
    float* __restrict__ s0out, float* __restrict__ s1out) {
    __shared__ float av0[768], av1[768];
    for (int t = threadIdx.x; t < 768; t += 256) {
        int hh = t / HD, d = t % HD;
        av0[t] = a[hh * 2 * HD + d];
        av1[t] = a[hh * 2 * HD + HD + d];
    }
    __syncthreads();
    int idx = blockIdx.x * 256 + threadIdx.x;   // (n,h)
    int row = idx >> 3, hh = idx & 7;
    const unsigned short* xp = X + (size_t)row * 768 + hh * HD;
    const float* a0 = av0 + hh * HD;
    const float* a1 = av1 + hh * HD;
    float s0 = 0.f, s1 = 0.f;
    #pragma unroll
    for (int q = 0; q < 12; q++) {
        u16x8 v = *(const u16x8*)(xp + q * 8);
        #pragma unroll
        for (int e = 0; e < 8; e++) {
            float x = bf2f(v[e]);
            s0 += x * a0[q * 8 + e];
            s1 += x * a1[q * 8 + e];
        }
    }
    s0out[idx] = s0;
    s1out[idx] = s1;
}

// single-half edge score (src scores for the merged counter/support table)
__global__ __launch_bounds__(256) void escore(
    const unsigned short* __restrict__ X, const float* __restrict__ a,
    int half, float* __restrict__ sc) {
    __shared__ float av[768];
    for (int t = threadIdx.x; t < 768; t += 256) {
        int hh = t / HD, d = t % HD;
        av[t] = a[hh * 2 * HD + half * HD + d];
    }
    __syncthreads();
    int idx = blockIdx.x * 256 + threadIdx.x;
    int row = idx >> 3, hh = idx & 7;
    const unsigned short* xp = X + (size_t)row * 768 + hh * HD;
    const float* ap = av + hh * HD;
    float s = 0.f;
    #pragma unroll
    for (int q = 0; q < 12; q++) {
        u16x8 v = *(const u16x8*)(xp + q * 8);
        #pragma unroll
        for (int e = 0; e < 8; e++) s += bf2f(v[e]) * ap[q * 8 + e];
    }
    sc[idx] = s;
}

// ---------------------------------------------------------------------------
// Folded dst-score: ED[n,h] = sum_f X[n,f]*wv[h,f] + cd[h].
// 8 threads per row, thread j covers f in [j*96, j*96+96); partials for all
// 8 heads in regs; 8-lane shfl reduction. wv staged as [j][h][97] (2-way max).
// ---------------------------------------------------------------------------
__global__ __launch_bounds__(256) void escore_fold(
    const unsigned short* __restrict__ X, const float* __restrict__ wv,
    const float* __restrict__ cd, float* __restrict__ ed) {
    __shared__ float wvs[8][8][97];
    __shared__ float cds[8];
    for (int i = threadIdx.x; i < 8 * 8 * 96; i += 256) {
        int j = i / (8 * 96); int r = i % (8 * 96); int h = r / 96; int t = r % 96;
        wvs[j][h][t] = wv[h * 768 + j * 96 + t];
    }
    if (threadIdx.x < 8) cds[threadIdx.x] = cd[threadIdx.x];
    __syncthreads();
    int idx = blockIdx.x * 256 + threadIdx.x;
    int n = idx >> 3, j = idx & 7;
    const unsigned short* xp = X + (size_t)n * 768 + j * 96;
    float p[8] = {};
    #pragma unroll
    for (int q = 0; q < 12; q++) {
        u16x8 v = *(const u16x8*)(xp + q * 8);
        #pragma unroll
        for (int e = 0; e < 8; e++) {
            float x = bf2f(v[e]);
            #pragma unroll
            for (int h = 0; h < 8; h++) p[h] += x * wvs[j][h][q * 8 + e];
        }
    }
    #pragma unroll
    for (int o = 1; o < 8; o <<= 1)
        #pragma unroll
        for (int h = 0; h < 8; h++) p[h] += __shfl_xor(p[h], o, 64);
    ed[(size_t)n * 8 + j] = p[j] + cds[j];
}

// ---------------------------------------------------------------------------
// Per-dst softmax + aggregate, one WAVE per dst segment. (intra branch)
// ---------------------------------------------------------------------------
__global__ __launch_bounds__(256) void attend_agg(
    const unsigned short* __restrict__ Whs, const float* __restrict__ es,
    const float* __restrict__ ed, const float* __restrict__ ab,
    const int* __restrict__ src, const int* __restrict__ dst,
    unsigned short* __restrict__ out) {
    const int wv = threadIdx.x >> 6, l = threadIdx.x & 63;
    const int seg = blockIdx.x * 4 + wv;
    const int hh = l >> 3, j = l & 7;
    int sj = src[seg * 8 + j];
    int dnode = dst[seg * 8];
    float e = es[(size_t)sj * 8 + hh] + ed[(size_t)dnode * 8 + hh] + ab[hh];
    e = e > 0.f ? e : LRELU_ALPHA * e;
    float m = e;
    #pragma unroll
    for (int o = 1; o < 8; o <<= 1) m = fmaxf(m, __shfl_xor(m, o, 64));
    float ex = expf(e - m);
    float s = ex;
    #pragma unroll
    for (int o = 1; o < 8; o <<= 1) s += __shfl_xor(s, o, 64);
    float att = ex / s;

    #pragma unroll
    for (int u = 0; u < 3; u++) {
        int c = 4 * l + 256 * u;
        int h = c / HD;
        float acc0 = 0.f, acc1 = 0.f, acc2 = 0.f, acc3 = 0.f;
        #pragma unroll
        for (int j2 = 0; j2 < 8; j2++) {
            float a = __shfl(att, h * 8 + j2, 64);
            int sid = __shfl(sj, j2, 64);
            u16x4 v = *(const u16x4*)(Whs + (size_t)sid * 768 + c);
            acc0 += a * bf2f(v[0]); acc1 += a * bf2f(v[1]);
            acc2 += a * bf2f(v[2]); acc3 += a * bf2f(v[3]);
        }
        u16x4 r;
        r[0] = f2bf(acc0); r[1] = f2bf(acc1); r[2] = f2bf(acc2); r[3] = f2bf(acc3);
        *(u16x4*)(out + (size_t)dnode * 768 + c) = r;
    }
}

// ---------------------------------------------------------------------------
// Fused counter+support attend: Hd = 0.5*attend(Wc, esC) + 0.5*attend(Ws, esS).
// ---------------------------------------------------------------------------
__global__ __launch_bounds__(256) void attend2(
    const unsigned short* __restrict__ Wc, const unsigned short* __restrict__ Ws,
    const float* __restrict__ esC, const float* __restrict__ esS,
    const float* __restrict__ ed, const float* __restrict__ ab,
    const int* __restrict__ csrc, const int* __restrict__ ssrc,
    const int* __restrict__ dst, unsigned short* __restrict__ outH) {
    const int wv = threadIdx.x >> 6, l = threadIdx.x & 63;
    const int seg = blockIdx.x * 4 + wv;
    const int hh = l >> 3, j = l & 7;
    int cj = csrc[seg * 8 + j];
    int sj = ssrc[seg * 8 + j];
    int dnode = dst[seg * 8];
    float edv = ed[(size_t)dnode * 8 + hh] + ab[hh];

    float eC = esC[(size_t)cj * 8 + hh] + edv;
    eC = eC > 0.f ? eC : LRELU_ALPHA * eC;
    float mC = eC;
    #pragma unroll
    for (int o = 1; o < 8; o <<= 1) mC = fmaxf(mC, __shfl_xor(mC, o, 64));
    float exC = expf(eC - mC);
    float sC = exC;
    #pragma unroll
    for (int o = 1; o < 8; o <<= 1) sC += __shfl_xor(sC, o, 64);
    float attC = exC / sC;

    float eS = esS[(size_t)sj * 8 + hh] + edv;
    eS = eS > 0.f ? eS : LRELU_ALPHA * eS;
    float mS = eS;
    #pragma unroll
    for (int o = 1; o < 8; o <<= 1) mS = fmaxf(mS, __shfl_xor(mS, o, 64));
    float exS = expf(eS - mS);
    float sS = exS;
    #pragma unroll
    for (int o = 1; o < 8; o <<= 1) sS += __shfl_xor(sS, o, 64);
    float attS = exS / sS;

    #pragma unroll
    for (int u = 0; u < 3; u++) {
        int c = 4 * l + 256 * u;
        int h = c / HD;
        float acc0 = 0.f, acc1 = 0.f, acc2 = 0.f, acc3 = 0.f;
        #pragma unroll
        for (int j2 = 0; j2 < 8; j2++) {
            float a = __shfl(attC, h * 8 + j2, 64);
            int sid = __shfl(cj, j2, 64);
            u16x4 v = *(const u16x4*)(Wc + (size_t)sid * 768 + c);
            acc0 += a * bf2f(v[0]); acc1 += a * bf2f(v[1]);
            acc2 += a * bf2f(v[2]); acc3 += a * bf2f(v[3]);
        }
        #pragma unroll
        for (int j2 = 0; j2 < 8; j2++) {
            float a = __shfl(attS, h * 8 + j2, 64);
            int sid = __shfl(sj, j2, 64);
            u16x4 v = *(const u16x4*)(Ws + (size_t)sid * 768 + c);
            acc0 += a * bf2f(v[0]); acc1 += a * bf2f(v[1]);
            acc2 += a * bf2f(v[2]); acc3 += a * bf2f(v[3]);
        }
        u16x4 r;
        r[0] = f2bf(0.5f * acc0); r[1] = f2bf(0.5f * acc1);
        r[2] = f2bf(0.5f * acc2); r[3] = f2bf(0.5f * acc3);
        *(u16x4*)(outH + (size_t)dnode * 768 + c) = r;
    }
}

// ---------------------------------------------------------------------------
// GRU elementwise tail (bf16 gi/gh/hid, f32 out), 8 cols/thread.
// ---------------------------------------------------------------------------
__global__ __launch_bounds__(256) void gru_elem(
    const unsigned short* __restrict__ gi, const unsigned short* __restrict__ gh,
    const unsigned short* __restrict__ hid, float* __restrict__ out) {
    int idx = blockIdx.x * 256 + threadIdx.x;   // over rows*96
    int nrow = idx / 96, c8 = (idx % 96) * 8;
    const unsigned short* gip = gi + (size_t)nrow * 2304 + c8;
    const unsigned short* ghp = gh + (size_t)nrow * 2304 + c8;
    u16x8 vir = *(const u16x8*)(gip);
    u16x8 viz = *(const u16x8*)(gip + 768);
    u16x8 vin = *(const u16x8*)(gip + 1536);
    u16x8 vhr = *(const u16x8*)(ghp);
    u16x8 vhz = *(const u16x8*)(ghp + 768);
    u16x8 vhn = *(const u16x8*)(ghp + 1536);
    u16x8 vh  = *(const u16x8*)(hid + (size_t)nrow * 768 + c8);
    float res[8];
    #pragma unroll
    for (int e = 0; e < 8; e++) {
        float r = 1.f / (1.f + expf(-(bf2f(vir[e]) + bf2f(vhr[e]))));
        float z = 1.f / (1.f + expf(-(bf2f(viz[e]) + bf2f(vhz[e]))));
        float cand = tanhf(bf2f(vin[e]) + r * bf2f(vhn[e]));
        res[e] = (1.f - z) * cand + z * bf2f(vh[e]);
    }
    float* op = out + (size_t)nrow * 768 + c8;
    *(float4*)(op)     = make_float4(res[0], res[1], res[2], res[3]);
    *(float4*)(op + 4) = make_float4(res[4], res[5], res[6], res[7]);
}

// ---------------------------------------------------------------------------
// Launch. ws (bf16 elems): Xb[SZ] | Hdb[SZ] | GIb[CH*2304] | GHb[CH*2304] |
//   W2gT W2xT WihB WhhB | f32: EScat[2NE] ED[NE] ESI[NE] EDI[NE] wv[6144] cd[8].
// ABcat (2NT*768 transient cvt buffer) aliases GIb/GHb (dead until GRU).
// Pcat (2NT*768 bf16 = both projections) lives in d_out. Total ws ~266 MB.
// ---------------------------------------------------------------------------
extern "C" void kernel_launch(void* const* d_in, const int* in_sizes, int n_in,
                              void* d_out, int out_size, void* d_ws, size_t ws_size,
                              hipStream_t stream) {
    const float* h    = (const float*)d_in[0];
    const float* hbc  = (const float*)d_in[1];
    const float* hbs  = (const float*)d_in[2];
    const float* Wg   = (const float*)d_in[3];
    const float* bg   = (const float*)d_in[4];
    const float* ag   = (const float*)d_in[5];
    const float* agb  = (const float*)d_in[6];
    const float* Wx   = (const float*)d_in[7];
    const float* bx   = (const float*)d_in[8];
    const float* ax   = (const float*)d_in[9];
    const float* axb  = (const float*)d_in[10];
    const float* Wih  = (const float*)d_in[11];
    const float* Whh  = (const float*)d_in[12];
    const float* bih  = (const float*)d_in[13];
    const float* bhh  = (const float*)d_in[14];
    const int* i_src  = (const int*)d_in[15];
    const int* i_dst  = (const int*)d_in[16];
    const int* c_src  = (const int*)d_in[17];
    const int* c_dst  = (const int*)d_in[18];
    const int* s_src  = (const int*)d_in[19];
    const int* s_dst  = (const int*)d_in[20];
    float* out = (float*)d_out;

    const size_t SZ = (size_t)NT * 768;
    unsigned short* Xb   = (unsigned short*)d_ws;
    unsigned short* Hdb  = Xb + SZ;
    unsigned short* GIb  = Hdb + SZ;
    unsigned short* GHb  = GIb + (size_t)CH * 2304;
    unsigned short* ABc  = GIb;                      // transient cvt buffer [2NT,768]
    unsigned short* ABs  = GIb + SZ;
    unsigned short* W2gT = GHb + (size_t)CH * 2304;
    unsigned short* W2xT = W2gT + 768 * 768;
    unsigned short* WihB = W2xT + 768 * 768;
    unsigned short* WhhB = WihB + 2304 * 768;
    float* EScat = (float*)(WhhB + 2304 * 768);      // [2NT*8]
    float* ED    = EScat + 2 * NE;
    float* ESI   = ED + NE;
    float* EDI   = ESI + NE;
    float* WV    = EDI + NE;                         // [8*768]
    float* CD    = WV + 8 * 768;                     // [8]
    unsigned short* Pcat = (unsigned short*)d_out;   // [2NT,768] bf16 scratch

    dim3 blk(256);
    packWT<<<(768 * 768 + 255) / 256, blk, 0, stream>>>(Wg, W2gT);
    packWT<<<(768 * 768 + 255) / 256, blk, 0, stream>>>(Wx, W2xT);
    cvt_bf8<<<(2304 * 768 / 8 + 255) / 256, blk, 0, stream>>>(Wih, WihB, 2304 * 768 / 8);
    cvt_bf8<<<(2304 * 768 / 8 + 255) / 256, blk, 0, stream>>>(Whh, WhhB, 2304 * 768 / 8);
    packWV<<<(8 * 768 + 255) / 256, blk, 0, stream>>>(Wx, ax, bx, WV, CD);

    dim3 g768(6, NT / 128);       // (6, 256)
    dim3 gcat(6, 2 * NT / 128);   // (6, 512)
    const int n8 = (int)(SZ / 8);
    const int cvtg = (n8 + 255) / 256;

    // 1) Wh = h @ Wg + bg -> Pcat[0:NT]
    cvt_bf8<<<cvtg, blk, 0, stream>>>(h, ABc, n8);
    mgemm_bb<<<g768, blk, 0, stream>>>(ABc, W2gT, bg, Pcat, NT, 768, 768);
    // 2) intra: dual scores in one pass, attend -> Xb
    escore2<<<NE / 256, blk, 0, stream>>>(Pcat, ag, ESI, EDI);
    attend_agg<<<NT / 4, blk, 0, stream>>>(Pcat, ESI, EDI, agb, i_src, i_dst, Xb);
    // 3) folded dst scores: ED = Xb @ wv^T + cd   (replaces the Wx_d GEMM)
    escore_fold<<<NE / 256, blk, 0, stream>>>(Xb, WV, CD, ED);
    // 4) merged counter+support projection -> Pcat [2NT,768]
    cvt_bf8<<<cvtg, blk, 0, stream>>>(hbc, ABc, n8);
    cvt_bf8<<<cvtg, blk, 0, stream>>>(hbs, ABs, n8);
    mgemm_bb<<<gcat, blk, 0, stream>>>(ABc, W2xT, bx, Pcat, 2 * NT, 768, 768);
    escore<<<2 * NE / 256, blk, 0, stream>>>(Pcat, ax, 0, EScat);
    // 5) fused counter+support attend -> Hdb
    attend2<<<NT / 4, blk, 0, stream>>>(Pcat, Pcat + SZ, EScat, EScat + NE, ED, axb,
                                        c_src, s_src, c_dst, Hdb);
    // 6) GRU, row-chunked (ABcat dead; GIb/GHb live)
    dim3 gch(2304 / 128, CH / 128);   // (18, 128)
    for (int c0 = 0; c0 < NT; c0 += CH) {
        mgemm_bb<<<gch, blk, 0, stream>>>(Xb  + (size_t)c0 * 768, WihB, bih, GIb, CH, 2304, 768);
        mgemm_bb<<<gch, blk, 0, stream>>>(Hdb + (size_t)c0 * 768, WhhB, bhh, GHb, CH, 2304, 768);
        gru_elem<<<(CH * 96) / 256, blk, 0, stream>>>(GIb, GHb, Hdb + (size_t)c0 * 768, out + (size_t)c0 * 768);
    }
}